// Round 3
// baseline (1885.050 us; speedup 1.0000x reference)
//
#include <hip/hip_runtime.h>
#include <hip/hip_bf16.h>
#include <math.h>

// Problem constants
#define Bn   2
#define Tn   2048
#define Cdim 1024
#define HSn  64
#define En   8
#define NRn  6
#define Pn   4
#define Hn   16            // C/HS
#define FFn  4096          // 4*C
#define NTn  2
#define BTn  4096          // B*T
#define CHL  128           // scan chunk length
#define NCH  16            // Tn/CHL

typedef __attribute__((ext_vector_type(8))) short bfrag;    // 8 bf16 (4 VGPRs)
typedef __attribute__((ext_vector_type(4))) float f32x4;

__device__ __forceinline__ void gl_lds16(const void* g, void* l) {
    __builtin_amdgcn_global_load_lds(
        (const __attribute__((address_space(1))) unsigned int*)g,
        (__attribute__((address_space(3))) unsigned int*)l, 16, 0, 0);
}

__device__ __forceinline__ float sigm(float v) { return 1.f / (1.f + expf(-v)); }

// ---------------- LayerNorm (ln1): fp32 in -> bf16 hi/lo ------
__global__ __launch_bounds__(256) void ln_kernel(const float* __restrict__ x,
                                                 const float* __restrict__ w,
                                                 const float* __restrict__ b,
                                                 float* __restrict__ out_f,
                                                 __hip_bfloat16* __restrict__ out_hi,
                                                 __hip_bfloat16* __restrict__ out_lo) {
    int row = blockIdx.x;
    const float* xr = x + (size_t)row * Cdim;
    float s = 0.f, s2 = 0.f;
    for (int c = threadIdx.x; c < Cdim; c += 256) {
        float v = xr[c];
        s += v; s2 += v * v;
    }
    __shared__ float rs[256], rs2[256];
    rs[threadIdx.x] = s; rs2[threadIdx.x] = s2;
    __syncthreads();
    for (int st = 128; st > 0; st >>= 1) {
        if (threadIdx.x < st) {
            rs[threadIdx.x]  += rs[threadIdx.x + st];
            rs2[threadIdx.x] += rs2[threadIdx.x + st];
        }
        __syncthreads();
    }
    float mean = rs[0] / Cdim;
    float var  = rs2[0] / Cdim - mean * mean;
    float inv  = rsqrtf(var + 1e-5f);
    for (int c = threadIdx.x; c < Cdim; c += 256) {
        float v = (xr[c] - mean) * inv * w[c] + b[c];
        size_t idx = (size_t)row * Cdim + c;
        if (out_f) out_f[idx] = v;
        if (out_hi) {
            __hip_bfloat16 hi = __float2bfloat16(v);
            out_hi[idx] = hi;
            if (out_lo) out_lo[idx] = __float2bfloat16(v - __bfloat162float(hi));
        }
    }
}

// ---------- fused ln2 + routing: LN -> bf16 h + winners/gates/counts ----------
__global__ __launch_bounds__(256) void ln2_routing_kernel(
    const float* __restrict__ x, const float* __restrict__ w,
    const float* __restrict__ b, __hip_bfloat16* __restrict__ out_hi,
    const float* __restrict__ conf_w, const float* __restrict__ conf_b,
    const float* __restrict__ Wa, const float* __restrict__ ba,
    const float* __restrict__ cap, int* __restrict__ meta,
    int2* __restrict__ winfo, float2* __restrict__ gvals) {
    int row = blockIdx.x;
    const float* xr = x + (size_t)row * Cdim;
    float s = 0.f, s2 = 0.f;
    for (int c = threadIdx.x; c < Cdim; c += 256) {
        float v = xr[c];
        s += v; s2 += v * v;
    }
    __shared__ float rs[256], rs2[256];
    rs[threadIdx.x] = s; rs2[threadIdx.x] = s2;
    __syncthreads();
    for (int st = 128; st > 0; st >>= 1) {
        if (threadIdx.x < st) {
            rs[threadIdx.x]  += rs[threadIdx.x + st];
            rs2[threadIdx.x] += rs2[threadIdx.x + st];
        }
        __syncthreads();
    }
    float mean = rs[0] / Cdim;
    float var  = rs2[0] / Cdim - mean * mean;
    float inv  = rsqrtf(var + 1e-5f);
    float pc[8], pa[8];
#pragma unroll
    for (int e = 0; e < 8; e++) { pc[e] = 0.f; pa[e] = 0.f; }
    for (int c = threadIdx.x; c < Cdim; c += 256) {
        float hv = (xr[c] - mean) * inv * w[c] + b[c];
        out_hi[(size_t)row * Cdim + c] = __float2bfloat16(hv);
#pragma unroll
        for (int e = 0; e < 8; e++) {
            pc[e] += hv * conf_w[(size_t)e * Cdim + c];
            pa[e] += hv * Wa[(size_t)c * En + e];
        }
    }
    __shared__ float red[256];
    __shared__ float vals[16];
    for (int e = 0; e < 16; e++) {
        red[threadIdx.x] = (e < 8) ? pc[e] : pa[e - 8];
        __syncthreads();
        for (int st = 128; st > 0; st >>= 1) {
            if (threadIdx.x < st) red[threadIdx.x] += red[threadIdx.x + st];
            __syncthreads();
        }
        if (threadIdx.x == 0) vals[e] = red[0];
        __syncthreads();
    }
    if (threadIdx.x == 0) {
        float conf[8], aff[8];
        for (int e = 0; e < 8; e++) {
            conf[e] = sigm(vals[e] + conf_b[e]);
            aff[e]  = vals[8 + e] + ba[e];
        }
        float mx = aff[0];
        for (int e = 1; e < 8; e++) mx = fmaxf(mx, aff[e]);
        float se = 0.f, ex[8];
        for (int e = 0; e < 8; e++) { ex[e] = expf(aff[e] - mx); se += ex[e]; }
        float bids[8];
        for (int e = 0; e < 8; e++) bids[e] = conf[e] * cap[e] + ex[e] / se;
        int w0 = 0;
        for (int e = 1; e < 8; e++) if (bids[e] > bids[w0]) w0 = e;
        int w1 = -1;
        for (int e = 0; e < 8; e++) {
            if (e == w0) continue;
            if (w1 < 0 || bids[e] > bids[w1]) w1 = e;
        }
        float e1 = expf(bids[w1] - bids[w0]);
        float g0 = 1.f / (1.f + e1);
        float g1 = e1 / (1.f + e1);
        winfo[row] = make_int2(w0, w1);
        gvals[row] = make_float2(g0, g1);
        atomicAdd(&meta[w0], 1);   // fire-and-forget
        atomicAdd(&meta[w1], 1);
    }
}

// ---------------- fp32 -> bf16 transposed weight conversion (plain) ------------
__global__ __launch_bounds__(256) void convT_kernel(const float* __restrict__ W,
                                                    __hip_bfloat16* __restrict__ Wt,
                                                    int K, int N) {
    __shared__ float tile[32][33];
    int k0 = blockIdx.y * 32, n0 = blockIdx.x * 32;
    int tx = threadIdx.x, ty = threadIdx.y;  // (32,8)
#pragma unroll
    for (int i = 0; i < 32; i += 8)
        tile[ty + i][tx] = W[(size_t)(k0 + ty + i) * N + n0 + tx];
    __syncthreads();
#pragma unroll
    for (int i = 0; i < 32; i += 8)
        Wt[(size_t)(n0 + ty + i) * K + k0 + tx] = __float2bfloat16(tile[tx][ty + i]);
}

// ---------------- fp32 -> split bf16 hi/lo transposed conversion ---------------
__global__ __launch_bounds__(256) void convT_split_kernel(const float* __restrict__ W,
                                                          __hip_bfloat16* __restrict__ Wh,
                                                          __hip_bfloat16* __restrict__ Wl,
                                                          int K, int N) {
    __shared__ float tile[32][33];
    int k0 = blockIdx.y * 32, n0 = blockIdx.x * 32;
    int tx = threadIdx.x, ty = threadIdx.y;  // (32,8)
#pragma unroll
    for (int i = 0; i < 32; i += 8)
        tile[ty + i][tx] = W[(size_t)(k0 + ty + i) * N + n0 + tx];
    __syncthreads();
#pragma unroll
    for (int i = 0; i < 32; i += 8) {
        float v = tile[tx][ty + i];
        __hip_bfloat16 hi = __float2bfloat16(v);
        size_t o = (size_t)(n0 + ty + i) * K + k0 + tx;
        Wh[o] = hi;
        Wl[o] = __float2bfloat16(v - __bfloat162float(hi));
    }
}

// ---- batched hi/lo split conversion: z selects one of 4 C×C matrices ----------
__global__ __launch_bounds__(256) void convT_split4_kernel(
    const float* __restrict__ W0, const float* __restrict__ W1,
    const float* __restrict__ W2, const float* __restrict__ W3,
    __hip_bfloat16* __restrict__ Wh, __hip_bfloat16* __restrict__ Wl) {
    int z = blockIdx.z;
    const float* W = (z == 0) ? W0 : (z == 1) ? W1 : (z == 2) ? W2 : W3;
    __hip_bfloat16* Whz = Wh + (size_t)z * Cdim * Cdim;
    __hip_bfloat16* Wlz = Wl + (size_t)z * Cdim * Cdim;
    __shared__ float tile[32][33];
    int k0 = blockIdx.y * 32, n0 = blockIdx.x * 32;
    int tx = threadIdx.x, ty = threadIdx.y;
#pragma unroll
    for (int i = 0; i < 32; i += 8)
        tile[ty + i][tx] = W[(size_t)(k0 + ty + i) * Cdim + n0 + tx];
    __syncthreads();
#pragma unroll
    for (int i = 0; i < 32; i += 8) {
        float v = tile[tx][ty + i];
        __hip_bfloat16 hi = __float2bfloat16(v);
        size_t o = (size_t)(n0 + ty + i) * Cdim + k0 + tx;
        Whz[o] = hi;
        Wlz[o] = __float2bfloat16(v - __bfloat162float(hi));
    }
}

// ---- batched FFN weight conversion: z=0 Wr, z=1..4 Wk N-slices, z=5..8 Wv K-slices
__global__ __launch_bounds__(256) void convT_ffn_kernel(
    const float* __restrict__ Wr, const float* __restrict__ Wk,
    const float* __restrict__ Wv, __hip_bfloat16* __restrict__ dRK,
    __hip_bfloat16* __restrict__ dV) {
    int z = blockIdx.z;
    const float* src; __hip_bfloat16* dst; int srcLD, dstLD;
    if (z == 0) {
        src = Wr; dst = dRK; srcLD = 1024; dstLD = 1024;
    } else if (z < 5) {
        int s = z - 1;
        src = Wk + (size_t)s * 1024;
        dst = dRK + (size_t)(1024 + s * 1024) * 1024;
        srcLD = FFn; dstLD = 1024;
    } else {
        int s = z - 5;
        src = Wv + (size_t)s * 1024 * Cdim;
        dst = dV + (size_t)s * 1024;
        srcLD = Cdim; dstLD = FFn;
    }
    __shared__ float tile[32][33];
    int k0 = blockIdx.y * 32, n0 = blockIdx.x * 32;
    int tx = threadIdx.x, ty = threadIdx.y;
#pragma unroll
    for (int i = 0; i < 32; i += 8)
        tile[ty + i][tx] = src[(size_t)(k0 + ty + i) * srcLD + n0 + tx];
    __syncthreads();
#pragma unroll
    for (int i = 0; i < 32; i += 8)
        dst[(size_t)(n0 + ty + i) * dstLD + k0 + tx] = __float2bfloat16(tile[tx][ty + i]);
}

// ---- batched TR weight conversion: z = expert*4 + {Wk,Wv,Wq,Wo}; dst 8*CC -----
__global__ __launch_bounds__(256) void convT_tr8_kernel(
    const float* __restrict__ Wk, const float* __restrict__ Wv,
    const float* __restrict__ Wq, const float* __restrict__ Wo,
    __hip_bfloat16* __restrict__ dst) {
    int z = blockIdx.z;
    int t = z >> 2, j = z & 3;
    const float* srcs[4] = {Wk, Wv, Wq, Wo};
    const float* W = srcs[j] + (size_t)t * Cdim * Cdim;
    __hip_bfloat16* Wt = dst + (size_t)z * Cdim * Cdim;
    __shared__ float tile[32][33];
    int k0 = blockIdx.y * 32, n0 = blockIdx.x * 32;
    int tx = threadIdx.x, ty = threadIdx.y;
#pragma unroll
    for (int i = 0; i < 32; i += 8)
        tile[ty + i][tx] = W[(size_t)(k0 + ty + i) * Cdim + n0 + tx];
    __syncthreads();
#pragma unroll
    for (int i = 0; i < 32; i += 8)
        Wt[(size_t)(n0 + ty + i) * Cdim + k0 + tx] = __float2bfloat16(tile[tx][ty + i]);
}

// LDS swizzle (64-elem rows): element (row r, chunk q of 8 bf16) at r*64 + ((q^(r&7))<<3).

// ---------- bf16x3 MFMA GEMM (fp32-grade): C = (Ah+Al)@(Bh+Bl)^T approx --------
enum { EP3_QKVW = 0, EP3_ADD = 1 };

template <int EP>
__global__ __launch_bounds__(256) void bgemm3_kernel(
    const __hip_bfloat16* __restrict__ Ah, const __hip_bfloat16* __restrict__ Al,
    const __hip_bfloat16* __restrict__ Bh, const __hip_bfloat16* __restrict__ Bl,
    float* __restrict__ o0, float* __restrict__ o1,
    float* __restrict__ o2, float* __restrict__ o3,
    int M, int N, int K, const float* __restrict__ aux) {
    __shared__ __align__(16) __hip_bfloat16 Ahs[8192], Als[8192], Bhs[8192], Bls[8192];
    int tid = threadIdx.x;
    int m0 = blockIdx.y * 128, n0 = blockIdx.x * 128;
    int l = tid & 63, wv = tid >> 6;
    int wm = (wv >> 1) * 64, wn = (wv & 1) * 64;
    int lr = l & 15, lq = l >> 4;

    f32x4 acc[4][4];
#pragma unroll
    for (int i = 0; i < 4; i++)
#pragma unroll
        for (int j = 0; j < 4; j++) acc[i][j] = (f32x4){0.f, 0.f, 0.f, 0.f};

    int srow = tid >> 3;
    int sq = (tid & 7) ^ (srow & 7);           // swizzled chunk
    size_t arow = (size_t)(m0 + srow) * K + (sq << 3);
    size_t brow = (size_t)(n0 + srow) * K + (sq << 3);

    for (int kt = 0; kt < K; kt += 64) {
#pragma unroll
        for (int c = 0; c < 4; c++) {
            size_t go = (size_t)(c * 32) * K + kt;
            gl_lds16(Ah + arow + go, Ahs + c * 2048 + tid * 8);
            gl_lds16(Al + arow + go, Als + c * 2048 + tid * 8);
            gl_lds16(Bh + brow + go, Bhs + c * 2048 + tid * 8);
            gl_lds16(Bl + brow + go, Bls + c * 2048 + tid * 8);
        }
        __syncthreads();
#pragma unroll
        for (int kc = 0; kc < 64; kc += 32) {
            bfrag ah[4], al[4], bh[4], bl[4];
#pragma unroll
            for (int mi = 0; mi < 4; mi++) {
                int rr = wm + mi * 16 + lr;
                int off = rr * 64 + ((((kc >> 3) + lq) ^ (rr & 7)) << 3);
                ah[mi] = *(const bfrag*)&Ahs[off];
                al[mi] = *(const bfrag*)&Als[off];
            }
#pragma unroll
            for (int ni = 0; ni < 4; ni++) {
                int rr = wn + ni * 16 + lr;
                int off = rr * 64 + ((((kc >> 3) + lq) ^ (rr & 7)) << 3);
                bh[ni] = *(const bfrag*)&Bhs[off];
                bl[ni] = *(const bfrag*)&Bls[off];
            }
#pragma unroll
            for (int mi = 0; mi < 4; mi++)
#pragma unroll
                for (int ni = 0; ni < 4; ni++) {
                    acc[mi][ni] = __builtin_amdgcn_mfma_f32_16x16x32_bf16(ah[mi], bh[ni], acc[mi][ni], 0, 0, 0);
                    acc[mi][ni] = __builtin_amdgcn_mfma_f32_16x16x32_bf16(al[mi], bh[ni], acc[mi][ni], 0, 0, 0);
                    acc[mi][ni] = __builtin_amdgcn_mfma_f32_16x16x32_bf16(ah[mi], bl[ni], acc[mi][ni], 0, 0, 0);
                }
        }
        __syncthreads();
    }

#pragma unroll
    for (int mi = 0; mi < 4; mi++) {
#pragma unroll
        for (int r = 0; r < 4; r++) {
            int row = m0 + wm + mi * 16 + lq * 4 + r;
#pragma unroll
            for (int ni = 0; ni < 4; ni++) {
                int col = n0 + wn + ni * 16 + lr;
                float v = acc[mi][ni][r];
                if (EP == EP3_QKVW) {
                    int sel = col >> 10, cc = col & 1023;
                    size_t idx = (size_t)row * 1024 + cc;
                    if (sel == 0) o0[idx] = v;
                    else if (sel == 1) o1[idx] = v;
                    else if (sel == 2) o2[idx] = v;
                    else o3[idx] = sigm(v + aux[cc]);
                } else {
                    size_t idx = (size_t)row * N + col;
                    o0[idx] = aux[idx] + v;
                }
            }
        }
    }
}

// ---------------- plain bf16 MFMA GEMM, sparse-expert-aware --------------------
// meta layout (ints): [0..7]=cnt, [8..15]=off
enum { EP_TANHB = 0, EP_Q = 1, EP_MOE = 2, EP_MOEM = 3, EP_FFN1 = 4, EP_KV = 5 };

template <int EP>
__global__ __launch_bounds__(256) void bgemm_kernel(
    const __hip_bfloat16* __restrict__ A, const __hip_bfloat16* __restrict__ Bt,
    void* __restrict__ Cv, void* __restrict__ Cv2, int M, int N, int K,
    const int* __restrict__ meta, int e,
    const int* __restrict__ tokidx, const float* __restrict__ tokgate,
    const float* __restrict__ aux2) {
    const size_t CC_ = (size_t)Cdim * Cdim;
    int rows = M;
    int offA = 0;
    int outoff = 0;
    const __hip_bfloat16* Bp = Bt;
    const int* sidx = nullptr;
    const float* sgate = nullptr;
    if (meta) {
        if (EP == EP_TANHB) {
            rows = meta[6] + meta[7];
        } else if (EP == EP_KV) {
            int zx = blockIdx.z;                  // expert 6+zx
            rows = meta[6 + zx] * 4;
            offA = (meta[8 + 6 + zx] - meta[14]) * 4;
            outoff = offA;
            Bp = Bt + (size_t)(zx * 4) * CC_;     // [Wk|Wv] pair
        } else if (EP == EP_Q) {
            int zx = blockIdx.z;
            rows = meta[6 + zx];
            offA = meta[8 + 6 + zx];
            outoff = meta[8 + 6 + zx] - meta[14];
            Bp = Bt + (size_t)(zx * 4 + 2) * CC_; // Wq
        } else if (EP == EP_MOE) {
            rows = meta[e];
            offA = meta[8 + e] - meta[14];        // attnc is lp-indexed
            sidx = tokidx + meta[8 + e];
            sgate = tokgate + meta[8 + e];
        } else if (EP == EP_MOEM) {
            rows = meta[e];
            sidx = tokidx + meta[8 + e];
            sgate = tokgate + meta[8 + e];
        } else {
            rows = meta[e];
            offA = meta[8 + e];
        }
    }
    int m0 = blockIdx.y * 128;
    if (m0 >= rows) return;

    __shared__ __align__(16) __hip_bfloat16 Asm[8192];
    __shared__ __align__(16) __hip_bfloat16 Bsm[8192];
    int tid = threadIdx.x;
    int n0 = blockIdx.x * 128;
    int l = tid & 63, wv = tid >> 6;
    int wm = (wv >> 1) * 64, wn = (wv & 1) * 64;
    int lr = l & 15, lq = l >> 4;

    f32x4 acc[4][4];
#pragma unroll
    for (int i = 0; i < 4; i++)
#pragma unroll
        for (int j = 0; j < 4; j++) acc[i][j] = (f32x4){0.f, 0.f, 0.f, 0.f};

    int srow = tid >> 3;
    int sq = (tid & 7) ^ (srow & 7);
    size_t arow = (size_t)(m0 + offA + srow) * K + (sq << 3);
    size_t brow = (size_t)(n0 + srow) * K + (sq << 3);

    int kbeg, kend;
    if (EP == EP_KV || EP == EP_Q) {              // z = expert, no k-split
        kbeg = 0; kend = K;
    } else {
        int ks = K / gridDim.z;
        kbeg = blockIdx.z * ks; kend = kbeg + ks;
    }

    for (int kt = kbeg; kt < kend; kt += 64) {
#pragma unroll
        for (int c = 0; c < 4; c++) {
            size_t go = (size_t)(c * 32) * K + kt;
            gl_lds16(A + arow + go, Asm + c * 2048 + tid * 8);
            gl_lds16(Bp + brow + go, Bsm + c * 2048 + tid * 8);
        }
        __syncthreads();
#pragma unroll
        for (int kc = 0; kc < 64; kc += 32) {
            bfrag af[4], bf[4];
#pragma unroll
            for (int mi = 0; mi < 4; mi++) {
                int rr = wm + mi * 16 + lr;
                af[mi] = *(const bfrag*)&Asm[rr * 64 + ((((kc >> 3) + lq) ^ (rr & 7)) << 3)];
            }
#pragma unroll
            for (int ni = 0; ni < 4; ni++) {
                int rr = wn + ni * 16 + lr;
                bf[ni] = *(const bfrag*)&Bsm[rr * 64 + ((((kc >> 3) + lq) ^ (rr & 7)) << 3)];
            }
#pragma unroll
            for (int mi = 0; mi < 4; mi++)
#pragma unroll
                for (int ni = 0; ni < 4; ni++)
                    acc[mi][ni] = __builtin_amdgcn_mfma_f32_16x16x32_bf16(
                        af[mi], bf[ni], acc[mi][ni], 0, 0, 0);
        }
        __syncthreads();
    }

    float* Cf = (float*)Cv;
    __hip_bfloat16* Cb = (__hip_bfloat16*)Cv;
#pragma unroll
    for (int mi = 0; mi < 4; mi++) {
#pragma unroll
        for (int r = 0; r < 4; r++) {
            int row = m0 + wm + mi * 16 + lq * 4 + r;
            if (row >= rows) continue;
            int orow = row + outoff;
            int t = 0; float g = 0.f;
            if (EP == EP_MOE || EP == EP_MOEM) { t = sidx[row]; g = sgate[row]; }
#pragma unroll
            for (int ni = 0; ni < 4; ni++) {
                int col = n0 + wn + ni * 16 + lr;
                float v = acc[mi][ni][r];
                if (EP == EP_TANHB) {
                    Cb[(size_t)row * N + col] = __float2bfloat16(tanhf(v));
                } else if (EP == EP_Q) {
                    Cb[(size_t)orow * N + col] = __float2bfloat16(v);
                } else if (EP == EP_MOE) {
                    float* p = Cf + (size_t)t * 1024 + col;
                    *p = *p + g * v;
                } else if (EP == EP_MOEM) {
                    atomicAdd(Cf + (size_t)t * 1024 + col,
                              g * aux2[(size_t)row * 1024 + col] * v);
                } else if (EP == EP_FFN1) {
                    if ((col >> 10) == 0) {
                        Cf[(size_t)row * 1024 + col] = sigm(v);
                    } else {
                        float q = fmaxf(v, 0.f);
                        ((__hip_bfloat16*)Cv2)[(size_t)row * 4096 + col - 1024] =
                            __float2bfloat16(q * q);
                    }
                } else if (EP == EP_KV) {
                    if ((col >> 10) == 0)
                        Cb[(size_t)orow * 1024 + col] = __float2bfloat16(v);
                    else
                        ((__hip_bfloat16*)Cv2)[(size_t)orow * 1024 + col - 1024] =
                            __float2bfloat16(v);
                }
            }
        }
    }
}

// ---------------- chunked RWKV scan (3 passes) ----------------
__global__ __launch_bounds__(256) void scan_pass1(
    const float* __restrict__ k, const float* __restrict__ v,
    const float* __restrict__ w, float* __restrict__ Mbuf,
    float* __restrict__ Pbuf) {
    int c = blockIdx.x, bh = blockIdx.y;
    int b = bh >> 4, h = bh & 15;
    int tid = threadIdx.x, j = tid & 63, ig = tid >> 6;
    __shared__ float sbuf[2][3][64];
    float S[16], P[16];
#pragma unroll
    for (int ii = 0; ii < 16; ii++) { S[ii] = 0.f; P[ii] = 1.f; }

    size_t base = ((size_t)b * Tn + (size_t)c * CHL) * Cdim + (size_t)h * HSn + j;
    const float* srcs[3] = {k, v, w};
    const float* myp = (ig > 0) ? srcs[ig - 1] + base : k + base;

    const int CH = 8;
    float buf[CH];
#pragma unroll
    for (int u = 0; u < CH; u++) buf[u] = (ig > 0) ? myp[(size_t)u * Cdim] : 0.f;

    for (int tc = 0; tc < CHL; tc += CH) {
        float nbuf[CH];
#pragma unroll
        for (int u = 0; u < CH; u++) {
            int t2 = tc + CH + u;
            nbuf[u] = (ig > 0 && t2 < CHL) ? myp[(size_t)t2 * Cdim] : 0.f;
        }
#pragma unroll
        for (int u = 0; u < CH; u++) {
            int p = (tc + u) & 1;
            if (ig > 0) sbuf[p][ig - 1][j] = buf[u];
            __syncthreads();
            float vj = sbuf[p][1][j];
            const float* skp = sbuf[p][0];
            const float* swp = sbuf[p][2];
#pragma unroll
            for (int ii = 0; ii < 16; ii++) {
                int i = (ig << 4) + ii;
                float wi = swp[i];
                S[ii] = S[ii] * wi + skp[i] * vj;
                P[ii] *= wi;
            }
        }
#pragma unroll
        for (int u = 0; u < CH; u++) buf[u] = nbuf[u];
    }
    size_t mo = ((size_t)c * 32 + bh) * 4096;
#pragma unroll
    for (int ii = 0; ii < 16; ii++)
        Mbuf[mo + (size_t)((ig << 4) + ii) * 64 + j] = S[ii];
    if (j == 0) {
#pragma unroll
        for (int ii = 0; ii < 16; ii++)
            Pbuf[((size_t)c * 32 + bh) * 64 + (ig << 4) + ii] = P[ii];
    }
}

__global__ __launch_bounds__(256) void scan_pass2(
    const float* __restrict__ Mbuf, const float* __restrict__ Pbuf,
    float* __restrict__ Sinb) {
    int bh = blockIdx.y;
    int idx = blockIdx.x * 256 + threadIdx.x;
    int i = idx >> 6;
    float S = 0.f;
    for (int c = 0; c < NCH; c++) {
        size_t o = ((size_t)c * 32 + bh);
        Sinb[o * 4096 + idx] = S;
        S = Pbuf[o * 64 + i] * S + Mbuf[o * 4096 + idx];
    }
}

__global__ __launch_bounds__(256) void scan_pass3(
    const float* __restrict__ r, const float* __restrict__ k,
    const float* __restrict__ v, const float* __restrict__ w,
    const float* __restrict__ Sinb,
    __hip_bfloat16* __restrict__ sh, __hip_bfloat16* __restrict__ sl) {
    int c = blockIdx.x, bh = blockIdx.y;
    int b = bh >> 4, h = bh & 15;
    int tid = threadIdx.x, j = tid & 63, ig = tid >> 6;
    __shared__ float sbuf[2][4][64];
    __shared__ float red[2][4][64];
    float S[16];
    size_t so = ((size_t)c * 32 + bh) * 4096;
#pragma unroll
    for (int ii = 0; ii < 16; ii++)
        S[ii] = Sinb[so + (size_t)((ig << 4) + ii) * 64 + j];

    size_t base = ((size_t)b * Tn + (size_t)c * CHL) * Cdim + (size_t)h * HSn + j;
    const float* srcs[4] = {r, k, v, w};
    const float* myp = srcs[ig] + base;

    const int CH = 8;
    float buf[CH];
#pragma unroll
    for (int u = 0; u < CH; u++) buf[u] = myp[(size_t)u * Cdim];
    float part_prev = 0.f;

    for (int tc = 0; tc < CHL; tc += CH) {
        float nbuf[CH];
#pragma unroll
        for (int u = 0; u < CH; u++) {
            int t2 = tc + CH + u;
            nbuf[u] = (t2 < CHL) ? myp[(size_t)t2 * Cdim] : 0.f;
        }
#pragma unroll
        for (int u = 0; u < CH; u++) {
            int t = tc + u;
            int p = t & 1;
            sbuf[p][ig][j] = buf[u];
            red[p][ig][j] = part_prev;
            __syncthreads();
            if (ig == 0 && t > 0) {
                float val = red[p][0][j] + red[p][1][j] + red[p][2][j] + red[p][3][j];
                __hip_bfloat16 hi = __float2bfloat16(val);
                size_t pos = base + (size_t)(t - 1) * Cdim;
                sh[pos] = hi;
                sl[pos] = __float2bfloat16(val - __bfloat162float(hi));
            }
            float vj = sbuf[p][2][j];
            const float* srp = sbuf[p][0];
            const float* skp = sbuf[p][1];
            const float* swp = sbuf[p][3];
            float part = 0.f;
#pragma unroll
            for (int ii = 0; ii < 16; ii++) {
                int i = (ig << 4) + ii;
                S[ii] = S[ii] * swp[i] + skp[i] * vj;
                part += srp[i] * S[ii];
            }
            part_prev = part;
        }
#pragma unroll
        for (int u = 0; u < CH; u++) buf[u] = nbuf[u];
    }
    red[0][ig][j] = part_prev;
    __syncthreads();
    if (ig == 0) {
        float val = red[0][0][j] + red[0][1][j] + red[0][2][j] + red[0][3][j];
        __hip_bfloat16 hi = __float2bfloat16(val);
        size_t pos = base + (size_t)(CHL - 1) * Cdim;
        sh[pos] = hi;
        sl[pos] = __float2bfloat16(val - __bfloat162float(hi));
    }
}

// ---- deterministic position assignment + offsets (no returning atomics) ------
// One block per expert; block e computes base = sum_{e'<e} cnt[e'] itself and
// publishes meta[8+e]; then LDS prefix-scan assigns compact rows.
__global__ __launch_bounds__(256) void assign_kernel(
    const int2* __restrict__ winfo, const float2* __restrict__ gvals,
    int* __restrict__ meta, int* __restrict__ tokidx,
    float* __restrict__ tokgate, int2* __restrict__ posbuf) {
    int e = blockIdx.x;
    int tid = threadIdx.x;
    __shared__ int scn[256];
    int base = 0;
    for (int e2 = 0; e2 < e; ++e2) base += meta[e2];
    if (tid == 0) meta[8 + e] = base;
    for (int c = 0; c < BTn; c += 256) {
        int t = c + tid;
        int2 w = winfo[t];
        int m0 = (w.x == e) ? 1 : 0;
        int m1 = (w.y == e) ? 1 : 0;
        int cnt = m0 + m1;          // w.x != w.y, so cnt is 0 or 1
        scn[tid] = cnt;
        __syncthreads();
        for (int st = 1; st < 256; st <<= 1) {
            int vv = (tid >= st) ? scn[tid - st] : 0;
            __syncthreads();
            scn[tid] += vv;
            __syncthreads();
        }
        int excl = scn[tid] - cnt;
        int tot = scn[255];
        if (m0) {
            int p = base + excl;
            tokidx[p] = t; tokgate[p] = gvals[t].x; posbuf[t].x = p;
        }
        if (m1) {
            int p = base + excl;
            tokidx[p] = t; tokgate[p] = gvals[t].y; posbuf[t].y = p;
        }
        base += tot;
        __syncthreads();
    }
}

// ---------------- gather compact activations (pure copy, no atomics) -----------
__global__ __launch_bounds__(256) void gather_kernel(
    const __hip_bfloat16* __restrict__ h_bf, const __hip_bfloat16* __restrict__ st,
    const int2* __restrict__ winfo, const int2* __restrict__ posbuf,
    const int* __restrict__ meta,
    __hip_bfloat16* __restrict__ hc, __hip_bfloat16* __restrict__ hsc) {
    int t = blockIdx.x;
    int tid = threadIdx.x;
    int2 w = winfo[t];
    int2 p = posbuf[t];
    int off6 = meta[14];
    ushort4 hv = ((const ushort4*)(h_bf + (size_t)t * 1024))[tid];
    ((ushort4*)(hc + (size_t)p.x * 1024))[tid] = hv;
    ((ushort4*)(hc + (size_t)p.y * 1024))[tid] = hv;
    if (w.x >= 6) {
        int lp = p.x - off6;
        ((ushort4*)(hsc + (size_t)lp * 2048))[tid] = hv;
        ((ushort4*)(hsc + (size_t)lp * 2048 + 1024))[tid] =
            ((const ushort4*)(st + (size_t)t * 1024))[tid];
    }
    if (w.y >= 6) {
        int lp = p.y - off6;
        ((ushort4*)(hsc + (size_t)lp * 2048))[tid] = hv;
        ((ushort4*)(hsc + (size_t)lp * 2048 + 1024))[tid] =
            ((const ushort4*)(st + (size_t)t * 1024))[tid];
    }
}

// ------- transformer-expert prefix attention (both experts, lp-indexed) --------
__global__ __launch_bounds__(256) void tr_attn_kernel(
    const __hip_bfloat16* __restrict__ qc, const __hip_bfloat16* __restrict__ kpc,
    const __hip_bfloat16* __restrict__ vpc, __hip_bfloat16* __restrict__ attnc,
    const int* __restrict__ meta) {
    int cnt = meta[6] + meta[7];
    int idx = blockIdx.x * 4 + (threadIdx.x >> 6);   // lp * 16 + head
    int lane = threadIdx.x & 63;
    int n = idx >> 4, h = idx & 15;
    if (n >= cnt) return;
    float qd = __bfloat162float(qc[(size_t)n * Cdim + (size_t)h * HSn + lane]);
    float s[4];
#pragma unroll
    for (int p = 0; p < 4; p++) {
        float t = qd * __bfloat162float(kpc[((size_t)n * Pn + p) * Cdim + (size_t)h * HSn + lane]);
        for (int off = 32; off > 0; off >>= 1) t += __shfl_down(t, off);
        s[p] = __shfl(t, 0);
    }
    const float scale = 0.125f;
    float mx = fmaxf(fmaxf(s[0], s[1]), fmaxf(s[2], s[3])) * scale;
    float es = 0.f, a[4];
#pragma unroll
    for (int p = 0; p < 4; p++) { a[p] = expf(s[p] * scale - mx); es += a[p]; }
    float o = 0.f;
#pragma unroll
    for (int p = 0; p < 4; p++)
        o += (a[p] / es) * __bfloat162float(vpc[((size_t)n * Pn + p) * Cdim + (size_t)h * HSn + lane]);
    attnc[(size_t)n * Cdim + (size_t)h * HSn + lane] = __float2bfloat16(o);
}

// ---------------- orchestration ----------------
extern "C" void kernel_launch(void* const* d_in, const int* in_sizes, int n_in,
                              void* d_out, int out_size, void* d_ws, size_t ws_size,
                              hipStream_t stream) {
    const float* x      = (const float*)d_in[0];
    const float* cap    = (const float*)d_in[2];
    const float* ln1_w  = (const float*)d_in[3];
    const float* ln1_b  = (const float*)d_in[4];
    const float* ln2_w  = (const float*)d_in[5];
    const float* ln2_b  = (const float*)d_in[6];
    const float* Wr     = (const float*)d_in[7];
    const float* Wk     = (const float*)d_in[8];
    const float* Wv     = (const float*)d_in[9];
    const float* Ww     = (const float*)d_in[10];
    const float* w_bias = (const float*)d_in[11];
    const float* Wo     = (const float*)d_in[12];
    const float* conf_w = (const float*)d_in[13];
    const float* conf_b = (const float*)d_in[14];
    const float* Wa     = (const float*)d_in[17];
    const float* ba     = (const float*)d_in[18];
    const float* Wb     = (const float*)d_in[19];
    const float* ffn_Wr = (const float*)d_in[20];
    const float* ffn_Wk = (const float*)d_in[21];
    const float* ffn_Wv = (const float*)d_in[22];
    const float* tr_Wq  = (const float*)d_in[23];
    const float* tr_Wk  = (const float*)d_in[24];
    const float* tr_Wv  = (const float*)d_in[25];
    const float* tr_Wo  = (const float*)d_in[26];

    float* xout  = (float*)d_out;
    float* vflat = (float*)d_out + (size_t)BTn * Cdim;

    char* ws = (char*)d_ws;
    const size_t MB = 1ull << 20;
    // attention phase
    __hip_bfloat16* xln_hi  = (__hip_bfloat16*)(ws + 0 * MB);
    __hip_bfloat16* xln_lo  = (__hip_bfloat16*)(ws + 8 * MB);
    __hip_bfloat16* Wall_hi = (__hip_bfloat16*)(ws + 16 * MB);
    __hip_bfloat16* Wall_lo = (__hip_bfloat16*)(ws + 24 * MB);
    float*          rbuf    = (float*)(ws + 32 * MB);
    float*          kbuf    = (float*)(ws + 48 * MB);
    float*          wbuf    = (float*)(ws + 64 * MB);
    float*          Pbuf    = (float*)(ws + 80 * MB);
    __hip_bfloat16* Wo_hi   = (__hip_bfloat16*)(ws + 81 * MB);
    __hip_bfloat16* Wo_lo   = (__hip_bfloat16*)(ws + 83 * MB);
    float*          Mbuf    = (float*)(ws + 0 * MB);    // over xln (dead)
    float*          Sinb    = (float*)(ws + 8 * MB);
    __hip_bfloat16* st_hi   = (__hip_bfloat16*)(ws + 16 * MB);  // over Wall (dead)
    __hip_bfloat16* st_lo   = (__hip_bfloat16*)(ws + 24 * MB);
    __hip_bfloat16* h_bf    = (__hip_bfloat16*)(ws + 48 * MB);  // over kbuf (dead)
    // compact expert structures
    __hip_bfloat16* hc      = (__hip_bfloat16*)(ws + 56 * MB);  // 8320 rows, 56-74
    __hip_bfloat16* hsc     = (__hip_bfloat16*)(ws + 74 * MB);  // 74-108
    __hip_bfloat16* Wt_b    = (__hip_bfloat16*)(ws + 108 * MB); // 16MB, 108-124
    __hip_bfloat16* prefixc = (__hip_bfloat16*)(ws + 124 * MB); // 68MB, 124-192
    // FFN phase (hsc/Wt_b dead after prefix GEMM)
    __hip_bfloat16* eWall   = (__hip_bfloat16*)(ws + 0 * MB);   // 10MB
    __hip_bfloat16* eWv_t   = (__hip_bfloat16*)(ws + 10 * MB);  // 8MB
    float*          rg      = (float*)(ws + 18 * MB);           // 17MB, 18-35
    __hip_bfloat16* kk      = (__hip_bfloat16*)(ws + 74 * MB);  // 35MB, 74-109
    // TR phase (FFN temporaries dead); all lp-indexed (both experts contiguous)
    __hip_bfloat16* vpc     = (__hip_bfloat16*)(ws + 0 * MB);   // 34MB, 0-34
    __hip_bfloat16* tkv     = (__hip_bfloat16*)(ws + 34 * MB);  // 16MB (8 CxC), 34-50
    __hip_bfloat16* kpc     = (__hip_bfloat16*)(ws + 74 * MB);  // 34MB, 74-108
    __hip_bfloat16* qc      = (__hip_bfloat16*)(ws + 108 * MB); // 16MB, 108-124
    __hip_bfloat16* attnc   = (__hip_bfloat16*)(ws + 192 * MB); // 8MB, 192-200
    // routing metadata
    int*    meta    = (int*)(ws + 200 * MB);                    // [cnt8|off8|spare8]
    int*    tokidx  = (int*)(ws + 200 * MB + (64 << 10));
    float*  tokgate = (float*)(ws + 200 * MB + (128 << 10));
    int2*   winfo   = (int2*)(ws + 200 * MB + (192 << 10));
    float2* gvals   = (float2*)(ws + 200 * MB + (256 << 10));
    int2*   posbuf  = (int2*)(ws + 200 * MB + (320 << 10));
    (void)ws_size; (void)in_sizes; (void)n_in; (void)out_size;

    dim3 blk(256);
    dim3 tblk(32, 8);
    auto grid  = [](int M, int N) { return dim3(N / 128, M / 128); };
    auto tgrid = [](int K, int N) { return dim3(N / 32, K / 32); };
    const size_t CC = (size_t)Cdim * Cdim;

    // 0. weight conversions (batched) + meta zero
    hipMemsetAsync(meta, 0, 96, stream);
    convT_split4_kernel<<<dim3(32, 32, 4), tblk, 0, stream>>>(Wr, Wk, Wv, Ww, Wall_hi, Wall_lo);
    convT_split_kernel<<<tgrid(Cdim, Cdim), tblk, 0, stream>>>(Wo, Wo_hi, Wo_lo, Cdim, Cdim);
    convT_kernel<<<tgrid(2 * Cdim, Pn * Cdim), tblk, 0, stream>>>(Wb, Wt_b, 2 * Cdim, Pn * Cdim);

    // 1. ln1 -> hi/lo
    ln_kernel<<<BTn, blk, 0, stream>>>(x, ln1_w, ln1_b, nullptr, xln_hi, xln_lo);
    // 2. fused r/k/v/w projections (bf16x3, BK=64)
    bgemm3_kernel<EP3_QKVW><<<grid(BTn, 4 * Cdim), blk, 0, stream>>>(
        xln_hi, xln_lo, Wall_hi, Wall_lo, rbuf, kbuf, vflat, wbuf, BTn, 4 * Cdim, Cdim, w_bias);
    // 3. chunked scan
    scan_pass1<<<dim3(NCH, 32), blk, 0, stream>>>(kbuf, vflat, wbuf, Mbuf, Pbuf);
    scan_pass2<<<dim3(16, 32), blk, 0, stream>>>(Mbuf, Pbuf, Sinb);
    scan_pass3<<<dim3(NCH, 32), blk, 0, stream>>>(rbuf, kbuf, vflat, wbuf, Sinb, st_hi, st_lo);
    // 4. x_after_att = x + state @ Wo
    bgemm3_kernel<EP3_ADD><<<grid(BTn, Cdim), blk, 0, stream>>>(
        st_hi, st_lo, Wo_hi, Wo_lo, xout, nullptr, nullptr, nullptr, BTn, Cdim, Cdim, x);
    // 5+6. fused ln2 + routing (no fp32 h roundtrip)
    ln2_routing_kernel<<<BTn, blk, 0, stream>>>(
        xout, ln2_w, ln2_b, h_bf, conf_w, conf_b, Wa, ba, cap, meta, winfo, gvals);
    // 6b. deterministic compact-row assignment (computes offsets internally)
    assign_kernel<<<dim3(8), blk, 0, stream>>>(winfo, gvals, meta, tokidx, tokgate, posbuf);
    // 7. gather compact activations (hc for all, hsc for TR winners)
    gather_kernel<<<BTn, blk, 0, stream>>>(h_bf, st_hi, winfo, posbuf, meta, hc, hsc);
    // 8. sparse bridge prefix = tanh(hsc @ Wb) over TR rows only
    bgemm_kernel<EP_TANHB><<<grid(2 * BTn, Pn * Cdim), blk, 0, stream>>>(
        hsc, Wt_b, prefixc, nullptr, 2 * BTn, Pn * Cdim, 2 * Cdim, meta, 0, nullptr, nullptr, nullptr);
    // 9. FFN experts (sparse); per-expert conversion batched into one z=9 dispatch
    for (int e = 0; e < NRn; e++) {
        convT_ffn_kernel<<<dim3(32, 32, 9), tblk, 0, stream>>>(
            ffn_Wr + (size_t)e * CC, ffn_Wk + (size_t)e * Cdim * FFn,
            ffn_Wv + (size_t)e * FFn * Cdim, eWall, eWv_t);
        bgemm_kernel<EP_FFN1><<<grid(BTn, 5 * Cdim), blk, 0, stream>>>(
            hc, eWall, rg, kk, BTn, 5 * Cdim, Cdim, meta, e, nullptr, nullptr, nullptr);
        bgemm_kernel<EP_MOEM><<<dim3(Cdim / 128, BTn / 128, 2), blk, 0, stream>>>(
            kk, eWv_t, xout, nullptr, BTn, Cdim, FFn, meta, e, tokidx, tokgate, rg);
    }
    // 10. transformer experts, batched across both experts
    convT_tr8_kernel<<<dim3(32, 32, 8), tblk, 0, stream>>>(tr_Wk, tr_Wv, tr_Wq, tr_Wo, tkv);
    bgemm_kernel<EP_KV><<<dim3(16, 128, 2), blk, 0, stream>>>(
        prefixc, tkv, kpc, vpc, 4 * BTn, 2 * Cdim, Cdim, meta, 6, nullptr, nullptr, nullptr);
    bgemm_kernel<EP_Q><<<dim3(8, 32, 2), blk, 0, stream>>>(
        hc, tkv, qc, nullptr, BTn, Cdim, Cdim, meta, 6, nullptr, nullptr, nullptr);
    tr_attn_kernel<<<(BTn * Hn) / 4, blk, 0, stream>>>(qc, kpc, vpc, attnc, meta);
    for (int t = 0; t < NTn; t++) {
        bgemm_kernel<EP_MOE><<<grid(BTn, Cdim), blk, 0, stream>>>(
            attnc, tkv + (size_t)(4 * t + 3) * CC, xout, nullptr,
            BTn, Cdim, Cdim, meta, 6 + t, tokidx, tokgate, nullptr);
    }
}

// Round 4
// 1620.914 us; speedup vs baseline: 1.1630x; 1.1630x over previous
//
#include <hip/hip_runtime.h>
#include <hip/hip_bf16.h>
#include <math.h>

// Problem constants
#define Bn   2
#define Tn   2048
#define Cdim 1024
#define HSn  64
#define En   8
#define NRn  6
#define Pn   4
#define Hn   16            // C/HS
#define FFn  4096          // 4*C
#define NTn  2
#define BTn  4096          // B*T
#define CHL  128           // scan chunk length
#define NCH  16            // Tn/CHL

typedef __attribute__((ext_vector_type(8))) short bfrag;    // 8 bf16 (4 VGPRs)
typedef __attribute__((ext_vector_type(4))) float f32x4;

__device__ __forceinline__ void gl_lds16(const void* g, void* l) {
    __builtin_amdgcn_global_load_lds(
        (const __attribute__((address_space(1))) unsigned int*)g,
        (__attribute__((address_space(3))) unsigned int*)l, 16, 0, 0);
}

__device__ __forceinline__ float sigm(float v) { return 1.f / (1.f + expf(-v)); }

// ---------------- LayerNorm (ln1): fp32 in -> bf16 hi/lo ------
// wave-butterfly reduction: 2 barriers total (was 8-step LDS tree)
__global__ __launch_bounds__(256) void ln_kernel(const float* __restrict__ x,
                                                 const float* __restrict__ w,
                                                 const float* __restrict__ b,
                                                 float* __restrict__ out_f,
                                                 __hip_bfloat16* __restrict__ out_hi,
                                                 __hip_bfloat16* __restrict__ out_lo) {
    int row = blockIdx.x;
    const float* xr = x + (size_t)row * Cdim;
    int tid = threadIdx.x, l = tid & 63, wid = tid >> 6;
    float s = 0.f, s2 = 0.f;
    for (int c = tid; c < Cdim; c += 256) {
        float v = xr[c];
        s += v; s2 += v * v;
    }
#pragma unroll
    for (int off = 32; off > 0; off >>= 1) {
        s  += __shfl_xor(s, off);
        s2 += __shfl_xor(s2, off);
    }
    __shared__ float lnred[8];
    if (l == 0) { lnred[wid] = s; lnred[4 + wid] = s2; }
    __syncthreads();
    float ts  = lnred[0] + lnred[1] + lnred[2] + lnred[3];
    float ts2 = lnred[4] + lnred[5] + lnred[6] + lnred[7];
    float mean = ts / Cdim;
    float var  = ts2 / Cdim - mean * mean;
    float inv  = rsqrtf(var + 1e-5f);
    for (int c = tid; c < Cdim; c += 256) {
        float v = (xr[c] - mean) * inv * w[c] + b[c];
        size_t idx = (size_t)row * Cdim + c;
        if (out_f) out_f[idx] = v;
        if (out_hi) {
            __hip_bfloat16 hi = __float2bfloat16(v);
            out_hi[idx] = hi;
            if (out_lo) out_lo[idx] = __float2bfloat16(v - __bfloat162float(hi));
        }
    }
}

// ---------- fused ln2 + routing: LN -> bf16 h + winners/gates/counts ----------
// wave-butterfly for LN sums AND the 16 expert dot-products: 2 barriers total
// (was ~136 block-wide barriers -> 143us latency-bound, VALUBusy 6.8%).
__global__ __launch_bounds__(256) void ln2_routing_kernel(
    const float* __restrict__ x, const float* __restrict__ w,
    const float* __restrict__ b, __hip_bfloat16* __restrict__ out_hi,
    const float* __restrict__ conf_w, const float* __restrict__ conf_b,
    const float* __restrict__ Wa, const float* __restrict__ ba,
    const float* __restrict__ cap, int* __restrict__ meta,
    int2* __restrict__ winfo, float2* __restrict__ gvals) {
    int row = blockIdx.x;
    const float* xr = x + (size_t)row * Cdim;
    int tid = threadIdx.x, l = tid & 63, wid = tid >> 6;
    float s = 0.f, s2 = 0.f;
    for (int c = tid; c < Cdim; c += 256) {
        float v = xr[c];
        s += v; s2 += v * v;
    }
#pragma unroll
    for (int off = 32; off > 0; off >>= 1) {
        s  += __shfl_xor(s, off);
        s2 += __shfl_xor(s2, off);
    }
    __shared__ float lnred[8];
    if (l == 0) { lnred[wid] = s; lnred[4 + wid] = s2; }
    __syncthreads();
    float ts  = lnred[0] + lnred[1] + lnred[2] + lnred[3];
    float ts2 = lnred[4] + lnred[5] + lnred[6] + lnred[7];
    float mean = ts / Cdim;
    float var  = ts2 / Cdim - mean * mean;
    float inv  = rsqrtf(var + 1e-5f);

    float pc[8], pa[8];
#pragma unroll
    for (int e = 0; e < 8; e++) { pc[e] = 0.f; pa[e] = 0.f; }
    for (int c = tid; c < Cdim; c += 256) {
        float hv = (xr[c] - mean) * inv * w[c] + b[c];
        out_hi[(size_t)row * Cdim + c] = __float2bfloat16(hv);
#pragma unroll
        for (int e = 0; e < 8; e++) {
            pc[e] += hv * conf_w[(size_t)e * Cdim + c];
            pa[e] += hv * Wa[(size_t)c * En + e];
        }
    }
#pragma unroll
    for (int off = 32; off > 0; off >>= 1) {
#pragma unroll
        for (int e = 0; e < 8; e++) {
            pc[e] += __shfl_xor(pc[e], off);
            pa[e] += __shfl_xor(pa[e], off);
        }
    }
    __shared__ float ered[4][16];
    if (l == 0) {
#pragma unroll
        for (int e = 0; e < 8; e++) {
            ered[wid][e]     = pc[e];
            ered[wid][8 + e] = pa[e];
        }
    }
    __syncthreads();
    if (tid == 0) {
        float conf[8], aff[8];
#pragma unroll
        for (int e = 0; e < 8; e++) {
            float vc = ered[0][e] + ered[1][e] + ered[2][e] + ered[3][e];
            float va = ered[0][8 + e] + ered[1][8 + e] + ered[2][8 + e] + ered[3][8 + e];
            conf[e] = sigm(vc + conf_b[e]);
            aff[e]  = va + ba[e];
        }
        float mx = aff[0];
#pragma unroll
        for (int e = 1; e < 8; e++) mx = fmaxf(mx, aff[e]);
        float se = 0.f, ex[8];
#pragma unroll
        for (int e = 0; e < 8; e++) { ex[e] = expf(aff[e] - mx); se += ex[e]; }
        float bids[8];
#pragma unroll
        for (int e = 0; e < 8; e++) bids[e] = conf[e] * cap[e] + ex[e] / se;
        int w0 = 0;
#pragma unroll
        for (int e = 1; e < 8; e++) if (bids[e] > bids[w0]) w0 = e;
        float b0 = bids[w0];
        int w1 = -1; float b1 = -1e30f;
#pragma unroll
        for (int e = 0; e < 8; e++) {
            if (e == w0) continue;
            if (w1 < 0 || bids[e] > b1) { w1 = e; b1 = bids[e]; }
        }
        float e1 = expf(b1 - b0);
        float g0 = 1.f / (1.f + e1);
        float g1 = e1 / (1.f + e1);
        winfo[row] = make_int2(w0, w1);
        gvals[row] = make_float2(g0, g1);
        atomicAdd(&meta[w0], 1);   // fire-and-forget
        atomicAdd(&meta[w1], 1);
    }
}

// ---------------- fp32 -> bf16 transposed weight conversion (plain) ------------
__global__ __launch_bounds__(256) void convT_kernel(const float* __restrict__ W,
                                                    __hip_bfloat16* __restrict__ Wt,
                                                    int K, int N) {
    __shared__ float tile[32][33];
    int k0 = blockIdx.y * 32, n0 = blockIdx.x * 32;
    int tx = threadIdx.x, ty = threadIdx.y;  // (32,8)
#pragma unroll
    for (int i = 0; i < 32; i += 8)
        tile[ty + i][tx] = W[(size_t)(k0 + ty + i) * N + n0 + tx];
    __syncthreads();
#pragma unroll
    for (int i = 0; i < 32; i += 8)
        Wt[(size_t)(n0 + ty + i) * K + k0 + tx] = __float2bfloat16(tile[tx][ty + i]);
}

// ---------------- fp32 -> split bf16 hi/lo transposed conversion ---------------
__global__ __launch_bounds__(256) void convT_split_kernel(const float* __restrict__ W,
                                                          __hip_bfloat16* __restrict__ Wh,
                                                          __hip_bfloat16* __restrict__ Wl,
                                                          int K, int N) {
    __shared__ float tile[32][33];
    int k0 = blockIdx.y * 32, n0 = blockIdx.x * 32;
    int tx = threadIdx.x, ty = threadIdx.y;  // (32,8)
#pragma unroll
    for (int i = 0; i < 32; i += 8)
        tile[ty + i][tx] = W[(size_t)(k0 + ty + i) * N + n0 + tx];
    __syncthreads();
#pragma unroll
    for (int i = 0; i < 32; i += 8) {
        float v = tile[tx][ty + i];
        __hip_bfloat16 hi = __float2bfloat16(v);
        size_t o = (size_t)(n0 + ty + i) * K + k0 + tx;
        Wh[o] = hi;
        Wl[o] = __float2bfloat16(v - __bfloat162float(hi));
    }
}

// ---- batched hi/lo split conversion: z selects one of 4 C×C matrices ----------
__global__ __launch_bounds__(256) void convT_split4_kernel(
    const float* __restrict__ W0, const float* __restrict__ W1,
    const float* __restrict__ W2, const float* __restrict__ W3,
    __hip_bfloat16* __restrict__ Wh, __hip_bfloat16* __restrict__ Wl) {
    int z = blockIdx.z;
    const float* W = (z == 0) ? W0 : (z == 1) ? W1 : (z == 2) ? W2 : W3;
    __hip_bfloat16* Whz = Wh + (size_t)z * Cdim * Cdim;
    __hip_bfloat16* Wlz = Wl + (size_t)z * Cdim * Cdim;
    __shared__ float tile[32][33];
    int k0 = blockIdx.y * 32, n0 = blockIdx.x * 32;
    int tx = threadIdx.x, ty = threadIdx.y;
#pragma unroll
    for (int i = 0; i < 32; i += 8)
        tile[ty + i][tx] = W[(size_t)(k0 + ty + i) * Cdim + n0 + tx];
    __syncthreads();
#pragma unroll
    for (int i = 0; i < 32; i += 8) {
        float v = tile[tx][ty + i];
        __hip_bfloat16 hi = __float2bfloat16(v);
        size_t o = (size_t)(n0 + ty + i) * Cdim + k0 + tx;
        Whz[o] = hi;
        Wlz[o] = __float2bfloat16(v - __bfloat162float(hi));
    }
}

// ---- batched FFN weight conversion: z=0 Wr, z=1..4 Wk N-slices, z=5..8 Wv K-slices
__global__ __launch_bounds__(256) void convT_ffn_kernel(
    const float* __restrict__ Wr, const float* __restrict__ Wk,
    const float* __restrict__ Wv, __hip_bfloat16* __restrict__ dRK,
    __hip_bfloat16* __restrict__ dV) {
    int z = blockIdx.z;
    const float* src; __hip_bfloat16* dst; int srcLD, dstLD;
    if (z == 0) {
        src = Wr; dst = dRK; srcLD = 1024; dstLD = 1024;
    } else if (z < 5) {
        int s = z - 1;
        src = Wk + (size_t)s * 1024;
        dst = dRK + (size_t)(1024 + s * 1024) * 1024;
        srcLD = FFn; dstLD = 1024;
    } else {
        int s = z - 5;
        src = Wv + (size_t)s * 1024 * Cdim;
        dst = dV + (size_t)s * 1024;
        srcLD = Cdim; dstLD = FFn;
    }
    __shared__ float tile[32][33];
    int k0 = blockIdx.y * 32, n0 = blockIdx.x * 32;
    int tx = threadIdx.x, ty = threadIdx.y;
#pragma unroll
    for (int i = 0; i < 32; i += 8)
        tile[ty + i][tx] = src[(size_t)(k0 + ty + i) * srcLD + n0 + tx];
    __syncthreads();
#pragma unroll
    for (int i = 0; i < 32; i += 8)
        dst[(size_t)(n0 + ty + i) * dstLD + k0 + tx] = __float2bfloat16(tile[tx][ty + i]);
}

// ---- batched TR weight conversion: z = expert*4 + {Wk,Wv,Wq,Wo}; dst 8*CC -----
__global__ __launch_bounds__(256) void convT_tr8_kernel(
    const float* __restrict__ Wk, const float* __restrict__ Wv,
    const float* __restrict__ Wq, const float* __restrict__ Wo,
    __hip_bfloat16* __restrict__ dst) {
    int z = blockIdx.z;
    int t = z >> 2, j = z & 3;
    const float* srcs[4] = {Wk, Wv, Wq, Wo};
    const float* W = srcs[j] + (size_t)t * Cdim * Cdim;
    __hip_bfloat16* Wt = dst + (size_t)z * Cdim * Cdim;
    __shared__ float tile[32][33];
    int k0 = blockIdx.y * 32, n0 = blockIdx.x * 32;
    int tx = threadIdx.x, ty = threadIdx.y;
#pragma unroll
    for (int i = 0; i < 32; i += 8)
        tile[ty + i][tx] = W[(size_t)(k0 + ty + i) * Cdim + n0 + tx];
    __syncthreads();
#pragma unroll
    for (int i = 0; i < 32; i += 8)
        Wt[(size_t)(n0 + ty + i) * Cdim + k0 + tx] = __float2bfloat16(tile[tx][ty + i]);
}

// LDS swizzle (64-elem rows): element (row r, chunk q of 8 bf16) at r*64 + ((q^(r&7))<<3).

// ---------- bf16x3 MFMA GEMM (fp32-grade): C = (Ah+Al)@(Bh+Bl)^T approx --------
enum { EP3_QKVW = 0, EP3_ADD = 1 };

template <int EP>
__global__ __launch_bounds__(256) void bgemm3_kernel(
    const __hip_bfloat16* __restrict__ Ah, const __hip_bfloat16* __restrict__ Al,
    const __hip_bfloat16* __restrict__ Bh, const __hip_bfloat16* __restrict__ Bl,
    float* __restrict__ o0, float* __restrict__ o1,
    float* __restrict__ o2, float* __restrict__ o3,
    int M, int N, int K, const float* __restrict__ aux) {
    __shared__ __align__(16) __hip_bfloat16 Ahs[8192], Als[8192], Bhs[8192], Bls[8192];
    int tid = threadIdx.x;
    int m0 = blockIdx.y * 128, n0 = blockIdx.x * 128;
    int l = tid & 63, wv = tid >> 6;
    int wm = (wv >> 1) * 64, wn = (wv & 1) * 64;
    int lr = l & 15, lq = l >> 4;

    f32x4 acc[4][4];
#pragma unroll
    for (int i = 0; i < 4; i++)
#pragma unroll
        for (int j = 0; j < 4; j++) acc[i][j] = (f32x4){0.f, 0.f, 0.f, 0.f};

    int srow = tid >> 3;
    int sq = (tid & 7) ^ (srow & 7);           // swizzled chunk
    size_t arow = (size_t)(m0 + srow) * K + (sq << 3);
    size_t brow = (size_t)(n0 + srow) * K + (sq << 3);

    for (int kt = 0; kt < K; kt += 64) {
#pragma unroll
        for (int c = 0; c < 4; c++) {
            size_t go = (size_t)(c * 32) * K + kt;
            gl_lds16(Ah + arow + go, Ahs + c * 2048 + tid * 8);
            gl_lds16(Al + arow + go, Als + c * 2048 + tid * 8);
            gl_lds16(Bh + brow + go, Bhs + c * 2048 + tid * 8);
            gl_lds16(Bl + brow + go, Bls + c * 2048 + tid * 8);
        }
        __syncthreads();
#pragma unroll
        for (int kc = 0; kc < 64; kc += 32) {
            bfrag ah[4], al[4], bh[4], bl[4];
#pragma unroll
            for (int mi = 0; mi < 4; mi++) {
                int rr = wm + mi * 16 + lr;
                int off = rr * 64 + ((((kc >> 3) + lq) ^ (rr & 7)) << 3);
                ah[mi] = *(const bfrag*)&Ahs[off];
                al[mi] = *(const bfrag*)&Als[off];
            }
#pragma unroll
            for (int ni = 0; ni < 4; ni++) {
                int rr = wn + ni * 16 + lr;
                int off = rr * 64 + ((((kc >> 3) + lq) ^ (rr & 7)) << 3);
                bh[ni] = *(const bfrag*)&Bhs[off];
                bl[ni] = *(const bfrag*)&Bls[off];
            }
#pragma unroll
            for (int mi = 0; mi < 4; mi++)
#pragma unroll
                for (int ni = 0; ni < 4; ni++) {
                    acc[mi][ni] = __builtin_amdgcn_mfma_f32_16x16x32_bf16(ah[mi], bh[ni], acc[mi][ni], 0, 0, 0);
                    acc[mi][ni] = __builtin_amdgcn_mfma_f32_16x16x32_bf16(al[mi], bh[ni], acc[mi][ni], 0, 0, 0);
                    acc[mi][ni] = __builtin_amdgcn_mfma_f32_16x16x32_bf16(ah[mi], bl[ni], acc[mi][ni], 0, 0, 0);
                }
        }
        __syncthreads();
    }

#pragma unroll
    for (int mi = 0; mi < 4; mi++) {
#pragma unroll
        for (int r = 0; r < 4; r++) {
            int row = m0 + wm + mi * 16 + lq * 4 + r;
#pragma unroll
            for (int ni = 0; ni < 4; ni++) {
                int col = n0 + wn + ni * 16 + lr;
                float v = acc[mi][ni][r];
                if (EP == EP3_QKVW) {
                    int sel = col >> 10, cc = col & 1023;
                    size_t idx = (size_t)row * 1024 + cc;
                    if (sel == 0) o0[idx] = v;
                    else if (sel == 1) o1[idx] = v;
                    else if (sel == 2) o2[idx] = v;
                    else o3[idx] = sigm(v + aux[cc]);
                } else {
                    size_t idx = (size_t)row * N + col;
                    o0[idx] = aux[idx] + v;
                }
            }
        }
    }
}

// ---------------- plain bf16 MFMA GEMM, sparse-expert-aware --------------------
// meta layout (ints): [0..7]=cnt, [8..15]=off
enum { EP_TANHB = 0, EP_Q = 1, EP_MOE = 2, EP_MOEM = 3, EP_FFN1 = 4, EP_KV = 5 };

template <int EP>
__global__ __launch_bounds__(256) void bgemm_kernel(
    const __hip_bfloat16* __restrict__ A, const __hip_bfloat16* __restrict__ Bt,
    void* __restrict__ Cv, void* __restrict__ Cv2, int M, int N, int K,
    const int* __restrict__ meta, int e,
    const int* __restrict__ tokidx, const float* __restrict__ tokgate,
    const float* __restrict__ aux2) {
    const size_t CC_ = (size_t)Cdim * Cdim;
    int rows = M;
    int offA = 0;
    int outoff = 0;
    const __hip_bfloat16* Bp = Bt;
    const int* sidx = nullptr;
    const float* sgate = nullptr;
    if (meta) {
        if (EP == EP_TANHB) {
            rows = meta[6] + meta[7];
        } else if (EP == EP_KV) {
            int zx = blockIdx.z;                  // expert 6+zx
            rows = meta[6 + zx] * 4;
            offA = (meta[8 + 6 + zx] - meta[14]) * 4;
            outoff = offA;
            Bp = Bt + (size_t)(zx * 4) * CC_;     // [Wk|Wv] pair
        } else if (EP == EP_Q) {
            int zx = blockIdx.z;
            rows = meta[6 + zx];
            offA = meta[8 + 6 + zx];
            outoff = meta[8 + 6 + zx] - meta[14];
            Bp = Bt + (size_t)(zx * 4 + 2) * CC_; // Wq
        } else if (EP == EP_MOE) {
            rows = meta[e];
            offA = meta[8 + e] - meta[14];        // attnc is lp-indexed
            sidx = tokidx + meta[8 + e];
            sgate = tokgate + meta[8 + e];
        } else if (EP == EP_MOEM) {
            rows = meta[e];
            sidx = tokidx + meta[8 + e];
            sgate = tokgate + meta[8 + e];
        } else {
            rows = meta[e];
            offA = meta[8 + e];
        }
    }
    int m0 = blockIdx.y * 128;
    if (m0 >= rows) return;

    __shared__ __align__(16) __hip_bfloat16 Asm[8192];
    __shared__ __align__(16) __hip_bfloat16 Bsm[8192];
    int tid = threadIdx.x;
    int n0 = blockIdx.x * 128;
    int l = tid & 63, wv = tid >> 6;
    int wm = (wv >> 1) * 64, wn = (wv & 1) * 64;
    int lr = l & 15, lq = l >> 4;

    f32x4 acc[4][4];
#pragma unroll
    for (int i = 0; i < 4; i++)
#pragma unroll
        for (int j = 0; j < 4; j++) acc[i][j] = (f32x4){0.f, 0.f, 0.f, 0.f};

    int srow = tid >> 3;
    int sq = (tid & 7) ^ (srow & 7);
    size_t arow = (size_t)(m0 + offA + srow) * K + (sq << 3);
    size_t brow = (size_t)(n0 + srow) * K + (sq << 3);

    int kbeg, kend;
    if (EP == EP_KV || EP == EP_Q) {              // z = expert, no k-split
        kbeg = 0; kend = K;
    } else {
        int ks = K / gridDim.z;
        kbeg = blockIdx.z * ks; kend = kbeg + ks;
    }

    for (int kt = kbeg; kt < kend; kt += 64) {
#pragma unroll
        for (int c = 0; c < 4; c++) {
            size_t go = (size_t)(c * 32) * K + kt;
            gl_lds16(A + arow + go, Asm + c * 2048 + tid * 8);
            gl_lds16(Bp + brow + go, Bsm + c * 2048 + tid * 8);
        }
        __syncthreads();
#pragma unroll
        for (int kc = 0; kc < 64; kc += 32) {
            bfrag af[4], bf[4];
#pragma unroll
            for (int mi = 0; mi < 4; mi++) {
                int rr = wm + mi * 16 + lr;
                af[mi] = *(const bfrag*)&Asm[rr * 64 + ((((kc >> 3) + lq) ^ (rr & 7)) << 3)];
            }
#pragma unroll
            for (int ni = 0; ni < 4; ni++) {
                int rr = wn + ni * 16 + lr;
                bf[ni] = *(const bfrag*)&Bsm[rr * 64 + ((((kc >> 3) + lq) ^ (rr & 7)) << 3)];
            }
#pragma unroll
            for (int mi = 0; mi < 4; mi++)
#pragma unroll
                for (int ni = 0; ni < 4; ni++)
                    acc[mi][ni] = __builtin_amdgcn_mfma_f32_16x16x32_bf16(
                        af[mi], bf[ni], acc[mi][ni], 0, 0, 0);
        }
        __syncthreads();
    }

    float* Cf = (float*)Cv;
    __hip_bfloat16* Cb = (__hip_bfloat16*)Cv;
#pragma unroll
    for (int mi = 0; mi < 4; mi++) {
#pragma unroll
        for (int r = 0; r < 4; r++) {
            int row = m0 + wm + mi * 16 + lq * 4 + r;
            if (row >= rows) continue;
            int orow = row + outoff;
            int t = 0; float g = 0.f;
            if (EP == EP_MOE || EP == EP_MOEM) { t = sidx[row]; g = sgate[row]; }
#pragma unroll
            for (int ni = 0; ni < 4; ni++) {
                int col = n0 + wn + ni * 16 + lr;
                float v = acc[mi][ni][r];
                if (EP == EP_TANHB) {
                    Cb[(size_t)row * N + col] = __float2bfloat16(tanhf(v));
                } else if (EP == EP_Q) {
                    Cb[(size_t)orow * N + col] = __float2bfloat16(v);
                } else if (EP == EP_MOE) {
                    float* p = Cf + (size_t)t * 1024 + col;
                    *p = *p + g * v;
                } else if (EP == EP_MOEM) {
                    atomicAdd(Cf + (size_t)t * 1024 + col,
                              g * aux2[(size_t)row * 1024 + col] * v);
                } else if (EP == EP_FFN1) {
                    if ((col >> 10) == 0) {
                        Cf[(size_t)row * 1024 + col] = sigm(v);
                    } else {
                        float q = fmaxf(v, 0.f);
                        ((__hip_bfloat16*)Cv2)[(size_t)row * 4096 + col - 1024] =
                            __float2bfloat16(q * q);
                    }
                } else if (EP == EP_KV) {
                    if ((col >> 10) == 0)
                        Cb[(size_t)orow * 1024 + col] = __float2bfloat16(v);
                    else
                        ((__hip_bfloat16*)Cv2)[(size_t)orow * 1024 + col - 1024] =
                            __float2bfloat16(v);
                }
            }
        }
    }
}

// ---------------- chunked RWKV scan (3 passes) ----------------
__global__ __launch_bounds__(256) void scan_pass1(
    const float* __restrict__ k, const float* __restrict__ v,
    const float* __restrict__ w, float* __restrict__ Mbuf,
    float* __restrict__ Pbuf) {
    int c = blockIdx.x, bh = blockIdx.y;
    int b = bh >> 4, h = bh & 15;
    int tid = threadIdx.x, j = tid & 63, ig = tid >> 6;
    __shared__ float sbuf[2][3][64];
    float S[16], P[16];
#pragma unroll
    for (int ii = 0; ii < 16; ii++) { S[ii] = 0.f; P[ii] = 1.f; }

    size_t base = ((size_t)b * Tn + (size_t)c * CHL) * Cdim + (size_t)h * HSn + j;
    const float* srcs[3] = {k, v, w};
    const float* myp = (ig > 0) ? srcs[ig - 1] + base : k + base;

    const int CH = 8;
    float buf[CH];
#pragma unroll
    for (int u = 0; u < CH; u++) buf[u] = (ig > 0) ? myp[(size_t)u * Cdim] : 0.f;

    for (int tc = 0; tc < CHL; tc += CH) {
        float nbuf[CH];
#pragma unroll
        for (int u = 0; u < CH; u++) {
            int t2 = tc + CH + u;
            nbuf[u] = (ig > 0 && t2 < CHL) ? myp[(size_t)t2 * Cdim] : 0.f;
        }
#pragma unroll
        for (int u = 0; u < CH; u++) {
            int p = (tc + u) & 1;
            if (ig > 0) sbuf[p][ig - 1][j] = buf[u];
            __syncthreads();
            float vj = sbuf[p][1][j];
            const float* skp = sbuf[p][0];
            const float* swp = sbuf[p][2];
#pragma unroll
            for (int ii = 0; ii < 16; ii++) {
                int i = (ig << 4) + ii;
                float wi = swp[i];
                S[ii] = S[ii] * wi + skp[i] * vj;
                P[ii] *= wi;
            }
        }
#pragma unroll
        for (int u = 0; u < CH; u++) buf[u] = nbuf[u];
    }
    size_t mo = ((size_t)c * 32 + bh) * 4096;
#pragma unroll
    for (int ii = 0; ii < 16; ii++)
        Mbuf[mo + (size_t)((ig << 4) + ii) * 64 + j] = S[ii];
    if (j == 0) {
#pragma unroll
        for (int ii = 0; ii < 16; ii++)
            Pbuf[((size_t)c * 32 + bh) * 64 + (ig << 4) + ii] = P[ii];
    }
}

__global__ __launch_bounds__(256) void scan_pass2(
    const float* __restrict__ Mbuf, const float* __restrict__ Pbuf,
    float* __restrict__ Sinb) {
    int bh = blockIdx.y;
    int idx = blockIdx.x * 256 + threadIdx.x;
    int i = idx >> 6;
    float S = 0.f;
    for (int c = 0; c < NCH; c++) {
        size_t o = ((size_t)c * 32 + bh);
        Sinb[o * 4096 + idx] = S;
        S = Pbuf[o * 64 + i] * S + Mbuf[o * 4096 + idx];
    }
}

__global__ __launch_bounds__(256) void scan_pass3(
    const float* __restrict__ r, const float* __restrict__ k,
    const float* __restrict__ v, const float* __restrict__ w,
    const float* __restrict__ Sinb,
    __hip_bfloat16* __restrict__ sh, __hip_bfloat16* __restrict__ sl) {
    int c = blockIdx.x, bh = blockIdx.y;
    int b = bh >> 4, h = bh & 15;
    int tid = threadIdx.x, j = tid & 63, ig = tid >> 6;
    __shared__ float sbuf[2][4][64];
    __shared__ float red[2][4][64];
    float S[16];
    size_t so = ((size_t)c * 32 + bh) * 4096;
#pragma unroll
    for (int ii = 0; ii < 16; ii++)
        S[ii] = Sinb[so + (size_t)((ig << 4) + ii) * 64 + j];

    size_t base = ((size_t)b * Tn + (size_t)c * CHL) * Cdim + (size_t)h * HSn + j;
    const float* srcs[4] = {r, k, v, w};
    const float* myp = srcs[ig] + base;

    const int CH = 8;
    float buf[CH];
#pragma unroll
    for (int u = 0; u < CH; u++) buf[u] = myp[(size_t)u * Cdim];
    float part_prev = 0.f;

    for (int tc = 0; tc < CHL; tc += CH) {
        float nbuf[CH];
#pragma unroll
        for (int u = 0; u < CH; u++) {
            int t2 = tc + CH + u;
            nbuf[u] = (t2 < CHL) ? myp[(size_t)t2 * Cdim] : 0.f;
        }
#pragma unroll
        for (int u = 0; u < CH; u++) {
            int t = tc + u;
            int p = t & 1;
            sbuf[p][ig][j] = buf[u];
            red[p][ig][j] = part_prev;
            __syncthreads();
            if (ig == 0 && t > 0) {
                float val = red[p][0][j] + red[p][1][j] + red[p][2][j] + red[p][3][j];
                __hip_bfloat16 hi = __float2bfloat16(val);
                size_t pos = base + (size_t)(t - 1) * Cdim;
                sh[pos] = hi;
                sl[pos] = __float2bfloat16(val - __bfloat162float(hi));
            }
            float vj = sbuf[p][2][j];
            const float* srp = sbuf[p][0];
            const float* skp = sbuf[p][1];
            const float* swp = sbuf[p][3];
            float part = 0.f;
#pragma unroll
            for (int ii = 0; ii < 16; ii++) {
                int i = (ig << 4) + ii;
                S[ii] = S[ii] * swp[i] + skp[i] * vj;
                part += srp[i] * S[ii];
            }
            part_prev = part;
        }
#pragma unroll
        for (int u = 0; u < CH; u++) buf[u] = nbuf[u];
    }
    red[0][ig][j] = part_prev;
    __syncthreads();
    if (ig == 0) {
        float val = red[0][0][j] + red[0][1][j] + red[0][2][j] + red[0][3][j];
        __hip_bfloat16 hi = __float2bfloat16(val);
        size_t pos = base + (size_t)(CHL - 1) * Cdim;
        sh[pos] = hi;
        sl[pos] = __float2bfloat16(val - __bfloat162float(hi));
    }
}

// ---- deterministic position assignment + offsets (no returning atomics) ------
__global__ __launch_bounds__(256) void assign_kernel(
    const int2* __restrict__ winfo, const float2* __restrict__ gvals,
    int* __restrict__ meta, int* __restrict__ tokidx,
    float* __restrict__ tokgate, int2* __restrict__ posbuf) {
    int e = blockIdx.x;
    int tid = threadIdx.x;
    __shared__ int scn[256];
    int base = 0;
    for (int e2 = 0; e2 < e; ++e2) base += meta[e2];
    if (tid == 0) meta[8 + e] = base;
    for (int c = 0; c < BTn; c += 256) {
        int t = c + tid;
        int2 w = winfo[t];
        int m0 = (w.x == e) ? 1 : 0;
        int m1 = (w.y == e) ? 1 : 0;
        int cnt = m0 + m1;          // w.x != w.y, so cnt is 0 or 1
        scn[tid] = cnt;
        __syncthreads();
        for (int st = 1; st < 256; st <<= 1) {
            int vv = (tid >= st) ? scn[tid - st] : 0;
            __syncthreads();
            scn[tid] += vv;
            __syncthreads();
        }
        int excl = scn[tid] - cnt;
        int tot = scn[255];
        if (m0) {
            int p = base + excl;
            tokidx[p] = t; tokgate[p] = gvals[t].x; posbuf[t].x = p;
        }
        if (m1) {
            int p = base + excl;
            tokidx[p] = t; tokgate[p] = gvals[t].y; posbuf[t].y = p;
        }
        base += tot;
        __syncthreads();
    }
}

// ---------------- gather compact activations (pure copy, no atomics) -----------
__global__ __launch_bounds__(256) void gather_kernel(
    const __hip_bfloat16* __restrict__ h_bf, const __hip_bfloat16* __restrict__ st,
    const int2* __restrict__ winfo, const int2* __restrict__ posbuf,
    const int* __restrict__ meta,
    __hip_bfloat16* __restrict__ hc, __hip_bfloat16* __restrict__ hsc) {
    int t = blockIdx.x;
    int tid = threadIdx.x;
    int2 w = winfo[t];
    int2 p = posbuf[t];
    int off6 = meta[14];
    ushort4 hv = ((const ushort4*)(h_bf + (size_t)t * 1024))[tid];
    ((ushort4*)(hc + (size_t)p.x * 1024))[tid] = hv;
    ((ushort4*)(hc + (size_t)p.y * 1024))[tid] = hv;
    if (w.x >= 6) {
        int lp = p.x - off6;
        ((ushort4*)(hsc + (size_t)lp * 2048))[tid] = hv;
        ((ushort4*)(hsc + (size_t)lp * 2048 + 1024))[tid] =
            ((const ushort4*)(st + (size_t)t * 1024))[tid];
    }
    if (w.y >= 6) {
        int lp = p.y - off6;
        ((ushort4*)(hsc + (size_t)lp * 2048))[tid] = hv;
        ((ushort4*)(hsc + (size_t)lp * 2048 + 1024))[tid] =
            ((const ushort4*)(st + (size_t)t * 1024))[tid];
    }
}

// ------- transformer-expert prefix attention (both experts, lp-indexed) --------
__global__ __launch_bounds__(256) void tr_attn_kernel(
    const __hip_bfloat16* __restrict__ qc, const __hip_bfloat16* __restrict__ kpc,
    const __hip_bfloat16* __restrict__ vpc, __hip_bfloat16* __restrict__ attnc,
    const int* __restrict__ meta) {
    int cnt = meta[6] + meta[7];
    int idx = blockIdx.x * 4 + (threadIdx.x >> 6);   // lp * 16 + head
    int lane = threadIdx.x & 63;
    int n = idx >> 4, h = idx & 15;
    if (n >= cnt) return;
    float qd = __bfloat162float(qc[(size_t)n * Cdim + (size_t)h * HSn + lane]);
    float s[4];
#pragma unroll
    for (int p = 0; p < 4; p++) {
        float t = qd * __bfloat162float(kpc[((size_t)n * Pn + p) * Cdim + (size_t)h * HSn + lane]);
        for (int off = 32; off > 0; off >>= 1) t += __shfl_down(t, off);
        s[p] = __shfl(t, 0);
    }
    const float scale = 0.125f;
    float mx = fmaxf(fmaxf(s[0], s[1]), fmaxf(s[2], s[3])) * scale;
    float es = 0.f, a[4];
#pragma unroll
    for (int p = 0; p < 4; p++) { a[p] = expf(s[p] * scale - mx); es += a[p]; }
    float o = 0.f;
#pragma unroll
    for (int p = 0; p < 4; p++)
        o += (a[p] / es) * __bfloat162float(vpc[((size_t)n * Pn + p) * Cdim + (size_t)h * HSn + lane]);
    attnc[(size_t)n * Cdim + (size_t)h * HSn + lane] = __float2bfloat16(o);
}

// ---------------- orchestration ----------------
extern "C" void kernel_launch(void* const* d_in, const int* in_sizes, int n_in,
                              void* d_out, int out_size, void* d_ws, size_t ws_size,
                              hipStream_t stream) {
    const float* x      = (const float*)d_in[0];
    const float* cap    = (const float*)d_in[2];
    const float* ln1_w  = (const float*)d_in[3];
    const float* ln1_b  = (const float*)d_in[4];
    const float* ln2_w  = (const float*)d_in[5];
    const float* ln2_b  = (const float*)d_in[6];
    const float* Wr     = (const float*)d_in[7];
    const float* Wk     = (const float*)d_in[8];
    const float* Wv     = (const float*)d_in[9];
    const float* Ww     = (const float*)d_in[10];
    const float* w_bias = (const float*)d_in[11];
    const float* Wo     = (const float*)d_in[12];
    const float* conf_w = (const float*)d_in[13];
    const float* conf_b = (const float*)d_in[14];
    const float* Wa     = (const float*)d_in[17];
    const float* ba     = (const float*)d_in[18];
    const float* Wb     = (const float*)d_in[19];
    const float* ffn_Wr = (const float*)d_in[20];
    const float* ffn_Wk = (const float*)d_in[21];
    const float* ffn_Wv = (const float*)d_in[22];
    const float* tr_Wq  = (const float*)d_in[23];
    const float* tr_Wk  = (const float*)d_in[24];
    const float* tr_Wv  = (const float*)d_in[25];
    const float* tr_Wo  = (const float*)d_in[26];

    float* xout  = (float*)d_out;
    float* vflat = (float*)d_out + (size_t)BTn * Cdim;

    char* ws = (char*)d_ws;
    const size_t MB = 1ull << 20;
    // attention phase
    __hip_bfloat16* xln_hi  = (__hip_bfloat16*)(ws + 0 * MB);
    __hip_bfloat16* xln_lo  = (__hip_bfloat16*)(ws + 8 * MB);
    __hip_bfloat16* Wall_hi = (__hip_bfloat16*)(ws + 16 * MB);
    __hip_bfloat16* Wall_lo = (__hip_bfloat16*)(ws + 24 * MB);
    float*          rbuf    = (float*)(ws + 32 * MB);
    float*          kbuf    = (float*)(ws + 48 * MB);
    float*          wbuf    = (float*)(ws + 64 * MB);
    float*          Pbuf    = (float*)(ws + 80 * MB);
    __hip_bfloat16* Wo_hi   = (__hip_bfloat16*)(ws + 81 * MB);
    __hip_bfloat16* Wo_lo   = (__hip_bfloat16*)(ws + 83 * MB);
    float*          Mbuf    = (float*)(ws + 0 * MB);    // over xln (dead)
    float*          Sinb    = (float*)(ws + 8 * MB);
    __hip_bfloat16* st_hi   = (__hip_bfloat16*)(ws + 16 * MB);  // over Wall (dead)
    __hip_bfloat16* st_lo   = (__hip_bfloat16*)(ws + 24 * MB);
    __hip_bfloat16* h_bf    = (__hip_bfloat16*)(ws + 48 * MB);  // over kbuf (dead)
    // compact expert structures
    __hip_bfloat16* hc      = (__hip_bfloat16*)(ws + 56 * MB);  // 8320 rows, 56-74
    __hip_bfloat16* hsc     = (__hip_bfloat16*)(ws + 74 * MB);  // 74-108
    __hip_bfloat16* Wt_b    = (__hip_bfloat16*)(ws + 108 * MB); // 16MB, 108-124
    __hip_bfloat16* prefixc = (__hip_bfloat16*)(ws + 124 * MB); // 68MB, 124-192
    // FFN phase (hsc/Wt_b dead after prefix GEMM)
    __hip_bfloat16* eWall   = (__hip_bfloat16*)(ws + 0 * MB);   // 10MB
    __hip_bfloat16* eWv_t   = (__hip_bfloat16*)(ws + 10 * MB);  // 8MB
    float*          rg      = (float*)(ws + 18 * MB);           // 17MB, 18-35
    __hip_bfloat16* kk      = (__hip_bfloat16*)(ws + 74 * MB);  // 35MB, 74-109
    // TR phase (FFN temporaries dead); all lp-indexed (both experts contiguous)
    __hip_bfloat16* vpc     = (__hip_bfloat16*)(ws + 0 * MB);   // 34MB, 0-34
    __hip_bfloat16* tkv     = (__hip_bfloat16*)(ws + 34 * MB);  // 16MB (8 CxC), 34-50
    __hip_bfloat16* kpc     = (__hip_bfloat16*)(ws + 74 * MB);  // 34MB, 74-108
    __hip_bfloat16* qc      = (__hip_bfloat16*)(ws + 108 * MB); // 16MB, 108-124
    __hip_bfloat16* attnc   = (__hip_bfloat16*)(ws + 192 * MB); // 8MB, 192-200
    // routing metadata
    int*    meta    = (int*)(ws + 200 * MB);                    // [cnt8|off8|spare8]
    int*    tokidx  = (int*)(ws + 200 * MB + (64 << 10));
    float*  tokgate = (float*)(ws + 200 * MB + (128 << 10));
    int2*   winfo   = (int2*)(ws + 200 * MB + (192 << 10));
    float2* gvals   = (float2*)(ws + 200 * MB + (256 << 10));
    int2*   posbuf  = (int2*)(ws + 200 * MB + (320 << 10));
    (void)ws_size; (void)in_sizes; (void)n_in; (void)out_size;

    dim3 blk(256);
    dim3 tblk(32, 8);
    auto grid  = [](int M, int N) { return dim3(N / 128, M / 128); };
    auto tgrid = [](int K, int N) { return dim3(N / 32, K / 32); };
    const size_t CC = (size_t)Cdim * Cdim;

    // 0. weight conversions (batched) + meta zero
    hipMemsetAsync(meta, 0, 96, stream);
    convT_split4_kernel<<<dim3(32, 32, 4), tblk, 0, stream>>>(Wr, Wk, Wv, Ww, Wall_hi, Wall_lo);
    convT_split_kernel<<<tgrid(Cdim, Cdim), tblk, 0, stream>>>(Wo, Wo_hi, Wo_lo, Cdim, Cdim);
    convT_kernel<<<tgrid(2 * Cdim, Pn * Cdim), tblk, 0, stream>>>(Wb, Wt_b, 2 * Cdim, Pn * Cdim);

    // 1. ln1 -> hi/lo
    ln_kernel<<<BTn, blk, 0, stream>>>(x, ln1_w, ln1_b, nullptr, xln_hi, xln_lo);
    // 2. fused r/k/v/w projections (bf16x3, BK=64)
    bgemm3_kernel<EP3_QKVW><<<grid(BTn, 4 * Cdim), blk, 0, stream>>>(
        xln_hi, xln_lo, Wall_hi, Wall_lo, rbuf, kbuf, vflat, wbuf, BTn, 4 * Cdim, Cdim, w_bias);
    // 3. chunked scan
    scan_pass1<<<dim3(NCH, 32), blk, 0, stream>>>(kbuf, vflat, wbuf, Mbuf, Pbuf);
    scan_pass2<<<dim3(16, 32), blk, 0, stream>>>(Mbuf, Pbuf, Sinb);
    scan_pass3<<<dim3(NCH, 32), blk, 0, stream>>>(rbuf, kbuf, vflat, wbuf, Sinb, st_hi, st_lo);
    // 4. x_after_att = x + state @ Wo
    bgemm3_kernel<EP3_ADD><<<grid(BTn, Cdim), blk, 0, stream>>>(
        st_hi, st_lo, Wo_hi, Wo_lo, xout, nullptr, nullptr, nullptr, BTn, Cdim, Cdim, x);
    // 5+6. fused ln2 + routing (shuffle-reduced, 2 barriers)
    ln2_routing_kernel<<<BTn, blk, 0, stream>>>(
        xout, ln2_w, ln2_b, h_bf, conf_w, conf_b, Wa, ba, cap, meta, winfo, gvals);
    // 6b. deterministic compact-row assignment (computes offsets internally)
    assign_kernel<<<dim3(8), blk, 0, stream>>>(winfo, gvals, meta, tokidx, tokgate, posbuf);
    // 7. gather compact activations (hc for all, hsc for TR winners)
    gather_kernel<<<BTn, blk, 0, stream>>>(h_bf, st_hi, winfo, posbuf, meta, hc, hsc);
    // 8. sparse bridge prefix = tanh(hsc @ Wb) over TR rows only
    bgemm_kernel<EP_TANHB><<<grid(2 * BTn, Pn * Cdim), blk, 0, stream>>>(
        hsc, Wt_b, prefixc, nullptr, 2 * BTn, Pn * Cdim, 2 * Cdim, meta, 0, nullptr, nullptr, nullptr);
    // 9. FFN experts (sparse); per-expert conversion batched into one z=9 dispatch
    for (int e = 0; e < NRn; e++) {
        convT_ffn_kernel<<<dim3(32, 32, 9), tblk, 0, stream>>>(
            ffn_Wr + (size_t)e * CC, ffn_Wk + (size_t)e * Cdim * FFn,
            ffn_Wv + (size_t)e * FFn * Cdim, eWall, eWv_t);
        bgemm_kernel<EP_FFN1><<<grid(BTn, 5 * Cdim), blk, 0, stream>>>(
            hc, eWall, rg, kk, BTn, 5 * Cdim, Cdim, meta, e, nullptr, nullptr, nullptr);
        bgemm_kernel<EP_MOEM><<<dim3(Cdim / 128, BTn / 128, 2), blk, 0, stream>>>(
            kk, eWv_t, xout, nullptr, BTn, Cdim, FFn, meta, e, tokidx, tokgate, rg);
    }
    // 10. transformer experts, batched across both experts
    convT_tr8_kernel<<<dim3(32, 32, 8), tblk, 0, stream>>>(tr_Wk, tr_Wv, tr_Wq, tr_Wo, tkv);
    bgemm_kernel<EP_KV><<<dim3(16, 128, 2), blk, 0, stream>>>(
        prefixc, tkv, kpc, vpc, 4 * BTn, 2 * Cdim, Cdim, meta, 6, nullptr, nullptr, nullptr);
    bgemm_kernel<EP_Q><<<dim3(8, 32, 2), blk, 0, stream>>>(
        hc, tkv, qc, nullptr, BTn, Cdim, Cdim, meta, 6, nullptr, nullptr, nullptr);
    tr_attn_kernel<<<(BTn * Hn) / 4, blk, 0, stream>>>(qc, kpc, vpc, attnc, meta);
    for (int t = 0; t < NTn; t++) {
        bgemm_kernel<EP_MOE><<<grid(BTn, Cdim), blk, 0, stream>>>(
            attnc, tkv + (size_t)(4 * t + 3) * CC, xout, nullptr,
            BTn, Cdim, Cdim, meta, 6 + t, tokidx, tokgate, nullptr);
    }
}

// Round 5
// 1592.669 us; speedup vs baseline: 1.1836x; 1.0177x over previous
//
#include <hip/hip_runtime.h>
#include <hip/hip_bf16.h>
#include <math.h>

// Problem constants
#define Bn   2
#define Tn   2048
#define Cdim 1024
#define HSn  64
#define En   8
#define NRn  6
#define Pn   4
#define Hn   16            // C/HS
#define FFn  4096          // 4*C
#define NTn  2
#define BTn  4096          // B*T
#define CHL  128           // scan chunk length
#define NCH  16            // Tn/CHL

typedef __attribute__((ext_vector_type(8))) short bfrag;    // 8 bf16 (4 VGPRs)
typedef __attribute__((ext_vector_type(4))) float f32x4;

__device__ __forceinline__ void gl_lds16(const void* g, void* l) {
    __builtin_amdgcn_global_load_lds(
        (const __attribute__((address_space(1))) unsigned int*)g,
        (__attribute__((address_space(3))) unsigned int*)l, 16, 0, 0);
}

__device__ __forceinline__ float sigm(float v) { return 1.f / (1.f + expf(-v)); }

// ---------------- LayerNorm (ln1): fp32 in -> bf16 hi/lo, vectorized ----------
// 256 threads x float4 = 1024 cols exactly; wave butterfly + 1 barrier.
__global__ __launch_bounds__(256) void ln_kernel(const float* __restrict__ x,
                                                 const float* __restrict__ w,
                                                 const float* __restrict__ b,
                                                 float* __restrict__ out_f,
                                                 __hip_bfloat16* __restrict__ out_hi,
                                                 __hip_bfloat16* __restrict__ out_lo) {
    int row = blockIdx.x;
    const float* xr = x + (size_t)row * Cdim;
    int tid = threadIdx.x, l = tid & 63, wid = tid >> 6;
    int c4 = tid << 2;
    float4 v = *(const float4*)&xr[c4];
    float s  = v.x + v.y + v.z + v.w;
    float s2 = v.x * v.x + v.y * v.y + v.z * v.z + v.w * v.w;
#pragma unroll
    for (int off = 32; off > 0; off >>= 1) {
        s  += __shfl_xor(s, off);
        s2 += __shfl_xor(s2, off);
    }
    __shared__ float lnred[8];
    if (l == 0) { lnred[wid] = s; lnred[4 + wid] = s2; }
    __syncthreads();
    float ts  = lnred[0] + lnred[1] + lnred[2] + lnred[3];
    float ts2 = lnred[4] + lnred[5] + lnred[6] + lnred[7];
    float mean = ts / Cdim;
    float var  = ts2 / Cdim - mean * mean;
    float inv  = rsqrtf(var + 1e-5f);
    float4 wv4 = *(const float4*)&w[c4];
    float4 bv4 = *(const float4*)&b[c4];
    float h0 = (v.x - mean) * inv * wv4.x + bv4.x;
    float h1 = (v.y - mean) * inv * wv4.y + bv4.y;
    float h2 = (v.z - mean) * inv * wv4.z + bv4.z;
    float h3 = (v.w - mean) * inv * wv4.w + bv4.w;
    size_t idx = (size_t)row * Cdim + c4;
    if (out_f) {
        float4 of = {h0, h1, h2, h3};
        *(float4*)&out_f[idx] = of;
    }
    if (out_hi) {
        __hip_bfloat16 hh[4] = {__float2bfloat16(h0), __float2bfloat16(h1),
                                __float2bfloat16(h2), __float2bfloat16(h3)};
        *(ushort4*)&out_hi[idx] = *(ushort4*)hh;
        if (out_lo) {
            __hip_bfloat16 ll[4] = {
                __float2bfloat16(h0 - __bfloat162float(hh[0])),
                __float2bfloat16(h1 - __bfloat162float(hh[1])),
                __float2bfloat16(h2 - __bfloat162float(hh[2])),
                __float2bfloat16(h3 - __bfloat162float(hh[3]))};
            *(ushort4*)&out_lo[idx] = *(ushort4*)ll;
        }
    }
}

// ---------- fused ln2 + routing: LN -> bf16 h + winners/gates/counts ----------
// vectorized x/h; wave-butterfly reductions; 2 barriers total.
__global__ __launch_bounds__(256) void ln2_routing_kernel(
    const float* __restrict__ x, const float* __restrict__ w,
    const float* __restrict__ b, __hip_bfloat16* __restrict__ out_hi,
    const float* __restrict__ conf_w, const float* __restrict__ conf_b,
    const float* __restrict__ Wa, const float* __restrict__ ba,
    const float* __restrict__ cap, int* __restrict__ meta,
    int2* __restrict__ winfo, float2* __restrict__ gvals) {
    int row = blockIdx.x;
    const float* xr = x + (size_t)row * Cdim;
    int tid = threadIdx.x, l = tid & 63, wid = tid >> 6;
    int c4 = tid << 2;
    float4 v = *(const float4*)&xr[c4];
    float s  = v.x + v.y + v.z + v.w;
    float s2 = v.x * v.x + v.y * v.y + v.z * v.z + v.w * v.w;
#pragma unroll
    for (int off = 32; off > 0; off >>= 1) {
        s  += __shfl_xor(s, off);
        s2 += __shfl_xor(s2, off);
    }
    __shared__ float lnred[8];
    if (l == 0) { lnred[wid] = s; lnred[4 + wid] = s2; }
    __syncthreads();
    float ts  = lnred[0] + lnred[1] + lnred[2] + lnred[3];
    float ts2 = lnred[4] + lnred[5] + lnred[6] + lnred[7];
    float mean = ts / Cdim;
    float var  = ts2 / Cdim - mean * mean;
    float inv  = rsqrtf(var + 1e-5f);
    float4 wv4 = *(const float4*)&w[c4];
    float4 bv4 = *(const float4*)&b[c4];
    float h0 = (v.x - mean) * inv * wv4.x + bv4.x;
    float h1 = (v.y - mean) * inv * wv4.y + bv4.y;
    float h2 = (v.z - mean) * inv * wv4.z + bv4.z;
    float h3 = (v.w - mean) * inv * wv4.w + bv4.w;
    {
        __hip_bfloat16 hh[4] = {__float2bfloat16(h0), __float2bfloat16(h1),
                                __float2bfloat16(h2), __float2bfloat16(h3)};
        *(ushort4*)&out_hi[(size_t)row * Cdim + c4] = *(ushort4*)hh;
    }
    float pc[8], pa[8];
#pragma unroll
    for (int e = 0; e < 8; e++) { pc[e] = 0.f; pa[e] = 0.f; }
#pragma unroll
    for (int e = 0; e < 8; e++) {
        float4 cw = *(const float4*)&conf_w[(size_t)e * Cdim + c4];
        pc[e] = h0 * cw.x + h1 * cw.y + h2 * cw.z + h3 * cw.w;
    }
    float hv4[4] = {h0, h1, h2, h3};
#pragma unroll
    for (int j = 0; j < 4; j++) {
        float4 wa0 = *(const float4*)&Wa[(size_t)(c4 + j) * En];
        float4 wa1 = *(const float4*)&Wa[(size_t)(c4 + j) * En + 4];
        pa[0] += hv4[j] * wa0.x; pa[1] += hv4[j] * wa0.y;
        pa[2] += hv4[j] * wa0.z; pa[3] += hv4[j] * wa0.w;
        pa[4] += hv4[j] * wa1.x; pa[5] += hv4[j] * wa1.y;
        pa[6] += hv4[j] * wa1.z; pa[7] += hv4[j] * wa1.w;
    }
#pragma unroll
    for (int off = 32; off > 0; off >>= 1) {
#pragma unroll
        for (int e = 0; e < 8; e++) {
            pc[e] += __shfl_xor(pc[e], off);
            pa[e] += __shfl_xor(pa[e], off);
        }
    }
    __shared__ float ered[4][16];
    if (l == 0) {
#pragma unroll
        for (int e = 0; e < 8; e++) {
            ered[wid][e]     = pc[e];
            ered[wid][8 + e] = pa[e];
        }
    }
    __syncthreads();
    if (tid == 0) {
        float conf[8], aff[8];
#pragma unroll
        for (int e = 0; e < 8; e++) {
            float vc = ered[0][e] + ered[1][e] + ered[2][e] + ered[3][e];
            float va = ered[0][8 + e] + ered[1][8 + e] + ered[2][8 + e] + ered[3][8 + e];
            conf[e] = sigm(vc + conf_b[e]);
            aff[e]  = va + ba[e];
        }
        float mx = aff[0];
#pragma unroll
        for (int e = 1; e < 8; e++) mx = fmaxf(mx, aff[e]);
        float se = 0.f, ex[8];
#pragma unroll
        for (int e = 0; e < 8; e++) { ex[e] = expf(aff[e] - mx); se += ex[e]; }
        float bids[8];
#pragma unroll
        for (int e = 0; e < 8; e++) bids[e] = conf[e] * cap[e] + ex[e] / se;
        int w0 = 0;
#pragma unroll
        for (int e = 1; e < 8; e++) if (bids[e] > bids[w0]) w0 = e;
        float b0 = bids[w0];
        int w1 = -1; float b1 = -1e30f;
#pragma unroll
        for (int e = 0; e < 8; e++) {
            if (e == w0) continue;
            if (w1 < 0 || bids[e] > b1) { w1 = e; b1 = bids[e]; }
        }
        float e1 = expf(b1 - b0);
        float g0 = 1.f / (1.f + e1);
        float g1 = e1 / (1.f + e1);
        winfo[row] = make_int2(w0, w1);
        gvals[row] = make_float2(g0, g1);
        atomicAdd(&meta[w0], 1);   // fire-and-forget
        atomicAdd(&meta[w1], 1);
    }
}

// ---------- vectorized 64x64 transpose-convert core (float4 in, ushort4 out) ---
// LDS tile [64][65]: both phases verified <=2-way bank aliasing (free, m136).
template <bool SPLIT>
__device__ __forceinline__ void convT64_core(
    const float* __restrict__ src, int srcLD,
    __hip_bfloat16* __restrict__ dh, __hip_bfloat16* __restrict__ dl, int dstLD,
    int k0, int n0, float* tile) {
    int tid = threadIdx.x;
#pragma unroll
    for (int i = 0; i < 4; i++) {
        int f = i * 256 + tid;          // float4 index
        int row = f >> 4;               // 16 float4 per row
        int c4 = (f & 15) << 2;
        float4 v = *(const float4*)&src[(size_t)(k0 + row) * srcLD + n0 + c4];
        tile[row * 65 + c4 + 0] = v.x;
        tile[row * 65 + c4 + 1] = v.y;
        tile[row * 65 + c4 + 2] = v.z;
        tile[row * 65 + c4 + 3] = v.w;
    }
    __syncthreads();
#pragma unroll
    for (int i = 0; i < 4; i++) {
        int g = i * 256 + tid;
        int orow = g >> 4;              // 16 ushort4 per out row
        int oc4 = (g & 15) << 2;        // k offset within tile
        float a = tile[(oc4 + 0) * 65 + orow];
        float b = tile[(oc4 + 1) * 65 + orow];
        float c = tile[(oc4 + 2) * 65 + orow];
        float d = tile[(oc4 + 3) * 65 + orow];
        __hip_bfloat16 hh[4] = {__float2bfloat16(a), __float2bfloat16(b),
                                __float2bfloat16(c), __float2bfloat16(d)};
        size_t o = (size_t)(n0 + orow) * dstLD + k0 + oc4;
        *(ushort4*)&dh[o] = *(ushort4*)hh;
        if (SPLIT) {
            __hip_bfloat16 ll[4] = {
                __float2bfloat16(a - __bfloat162float(hh[0])),
                __float2bfloat16(b - __bfloat162float(hh[1])),
                __float2bfloat16(c - __bfloat162float(hh[2])),
                __float2bfloat16(d - __bfloat162float(hh[3]))};
            *(ushort4*)&dl[o] = *(ushort4*)ll;
        }
    }
}

// ---- z=0..3: Wr/Wk/Wv/Ww -> Wall hi/lo; z=4: Wo -> Wo hi/lo (all 1024^2) -----
__global__ __launch_bounds__(256) void convT_split5_kernel(
    const float* __restrict__ W0, const float* __restrict__ W1,
    const float* __restrict__ W2, const float* __restrict__ W3,
    const float* __restrict__ W4,
    __hip_bfloat16* __restrict__ Wall_h, __hip_bfloat16* __restrict__ Wall_l,
    __hip_bfloat16* __restrict__ Wo_h, __hip_bfloat16* __restrict__ Wo_l) {
    __shared__ float tile[64 * 65];
    int z = blockIdx.z;
    const float* srcs[5] = {W0, W1, W2, W3, W4};
    const float* src = srcs[z];
    __hip_bfloat16 *dh, *dl;
    if (z < 4) {
        dh = Wall_h + (size_t)z * Cdim * Cdim;
        dl = Wall_l + (size_t)z * Cdim * Cdim;
    } else {
        dh = Wo_h; dl = Wo_l;
    }
    convT64_core<true>(src, Cdim, dh, dl, Cdim, blockIdx.y * 64, blockIdx.x * 64, tile);
}

// ---- generic plain transpose-convert (used for Wb) ----------------------------
__global__ __launch_bounds__(256) void convT64_kernel(const float* __restrict__ W,
                                                      __hip_bfloat16* __restrict__ Wt,
                                                      int K, int N) {
    __shared__ float tile[64 * 65];
    convT64_core<false>(W, N, Wt, nullptr, K, blockIdx.y * 64, blockIdx.x * 64, tile);
}

// ---- batched FFN weight conversion: z=0 Wr, z=1..4 Wk N-slices, z=5..8 Wv K-slices
__global__ __launch_bounds__(256) void convT_ffn_kernel(
    const float* __restrict__ Wr, const float* __restrict__ Wk,
    const float* __restrict__ Wv, __hip_bfloat16* __restrict__ dRK,
    __hip_bfloat16* __restrict__ dV) {
    __shared__ float tile[64 * 65];
    int z = blockIdx.z;
    const float* src; __hip_bfloat16* dst; int srcLD, dstLD;
    if (z == 0) {
        src = Wr; dst = dRK; srcLD = 1024; dstLD = 1024;
    } else if (z < 5) {
        int s = z - 1;
        src = Wk + (size_t)s * 1024;
        dst = dRK + (size_t)(1024 + s * 1024) * 1024;
        srcLD = FFn; dstLD = 1024;
    } else {
        int s = z - 5;
        src = Wv + (size_t)s * 1024 * Cdim;
        dst = dV + (size_t)s * 1024;
        srcLD = Cdim; dstLD = FFn;
    }
    convT64_core<false>(src, srcLD, dst, nullptr, dstLD,
                        blockIdx.y * 64, blockIdx.x * 64, tile);
}

// ---- batched TR weight conversion: z = expert*4 + {Wk,Wv,Wq,Wo}; dst 8*CC -----
__global__ __launch_bounds__(256) void convT_tr8_kernel(
    const float* __restrict__ Wk, const float* __restrict__ Wv,
    const float* __restrict__ Wq, const float* __restrict__ Wo,
    __hip_bfloat16* __restrict__ dst) {
    __shared__ float tile[64 * 65];
    int z = blockIdx.z;
    int t = z >> 2, j = z & 3;
    const float* srcs[4] = {Wk, Wv, Wq, Wo};
    const float* W = srcs[j] + (size_t)t * Cdim * Cdim;
    __hip_bfloat16* Wt = dst + (size_t)z * Cdim * Cdim;
    convT64_core<false>(W, Cdim, Wt, nullptr, Cdim,
                        blockIdx.y * 64, blockIdx.x * 64, tile);
}

// LDS swizzle (64-elem rows): element (row r, chunk q of 8 bf16) at r*64 + ((q^(r&7))<<3).

// ---------- bf16x3 MFMA GEMM (fp32-grade): C = (Ah+Al)@(Bh+Bl)^T approx --------
enum { EP3_QKVW = 0, EP3_ADD = 1 };

template <int EP>
__global__ __launch_bounds__(256) void bgemm3_kernel(
    const __hip_bfloat16* __restrict__ Ah, const __hip_bfloat16* __restrict__ Al,
    const __hip_bfloat16* __restrict__ Bh, const __hip_bfloat16* __restrict__ Bl,
    float* __restrict__ o0, float* __restrict__ o1,
    float* __restrict__ o2, float* __restrict__ o3,
    int M, int N, int K, const float* __restrict__ aux) {
    __shared__ __align__(16) __hip_bfloat16 Ahs[8192], Als[8192], Bhs[8192], Bls[8192];
    int tid = threadIdx.x;
    int m0 = blockIdx.y * 128, n0 = blockIdx.x * 128;
    int l = tid & 63, wv = tid >> 6;
    int wm = (wv >> 1) * 64, wn = (wv & 1) * 64;
    int lr = l & 15, lq = l >> 4;

    f32x4 acc[4][4];
#pragma unroll
    for (int i = 0; i < 4; i++)
#pragma unroll
        for (int j = 0; j < 4; j++) acc[i][j] = (f32x4){0.f, 0.f, 0.f, 0.f};

    int srow = tid >> 3;
    int sq = (tid & 7) ^ (srow & 7);           // swizzled chunk
    size_t arow = (size_t)(m0 + srow) * K + (sq << 3);
    size_t brow = (size_t)(n0 + srow) * K + (sq << 3);

    for (int kt = 0; kt < K; kt += 64) {
#pragma unroll
        for (int c = 0; c < 4; c++) {
            size_t go = (size_t)(c * 32) * K + kt;
            gl_lds16(Ah + arow + go, Ahs + c * 2048 + tid * 8);
            gl_lds16(Al + arow + go, Als + c * 2048 + tid * 8);
            gl_lds16(Bh + brow + go, Bhs + c * 2048 + tid * 8);
            gl_lds16(Bl + brow + go, Bls + c * 2048 + tid * 8);
        }
        __syncthreads();
#pragma unroll
        for (int kc = 0; kc < 64; kc += 32) {
            bfrag ah[4], al[4], bh[4], bl[4];
#pragma unroll
            for (int mi = 0; mi < 4; mi++) {
                int rr = wm + mi * 16 + lr;
                int off = rr * 64 + ((((kc >> 3) + lq) ^ (rr & 7)) << 3);
                ah[mi] = *(const bfrag*)&Ahs[off];
                al[mi] = *(const bfrag*)&Als[off];
            }
#pragma unroll
            for (int ni = 0; ni < 4; ni++) {
                int rr = wn + ni * 16 + lr;
                int off = rr * 64 + ((((kc >> 3) + lq) ^ (rr & 7)) << 3);
                bh[ni] = *(const bfrag*)&Bhs[off];
                bl[ni] = *(const bfrag*)&Bls[off];
            }
#pragma unroll
            for (int mi = 0; mi < 4; mi++)
#pragma unroll
                for (int ni = 0; ni < 4; ni++) {
                    acc[mi][ni] = __builtin_amdgcn_mfma_f32_16x16x32_bf16(ah[mi], bh[ni], acc[mi][ni], 0, 0, 0);
                    acc[mi][ni] = __builtin_amdgcn_mfma_f32_16x16x32_bf16(al[mi], bh[ni], acc[mi][ni], 0, 0, 0);
                    acc[mi][ni] = __builtin_amdgcn_mfma_f32_16x16x32_bf16(ah[mi], bl[ni], acc[mi][ni], 0, 0, 0);
                }
        }
        __syncthreads();
    }

#pragma unroll
    for (int mi = 0; mi < 4; mi++) {
#pragma unroll
        for (int r = 0; r < 4; r++) {
            int row = m0 + wm + mi * 16 + lq * 4 + r;
#pragma unroll
            for (int ni = 0; ni < 4; ni++) {
                int col = n0 + wn + ni * 16 + lr;
                float v = acc[mi][ni][r];
                if (EP == EP3_QKVW) {
                    int sel = col >> 10, cc = col & 1023;
                    size_t idx = (size_t)row * 1024 + cc;
                    if (sel == 0) o0[idx] = v;
                    else if (sel == 1) o1[idx] = v;
                    else if (sel == 2) o2[idx] = v;
                    else o3[idx] = sigm(v + aux[cc]);
                } else {
                    size_t idx = (size_t)row * N + col;
                    o0[idx] = aux[idx] + v;
                }
            }
        }
    }
}

// ---------------- plain bf16 MFMA GEMM, sparse-expert-aware --------------------
// meta layout (ints): [0..7]=cnt, [8..15]=off
enum { EP_TANHB = 0, EP_Q = 1, EP_MOE = 2, EP_MOEM = 3, EP_FFN1 = 4, EP_KV = 5 };

template <int EP>
__global__ __launch_bounds__(256) void bgemm_kernel(
    const __hip_bfloat16* __restrict__ A, const __hip_bfloat16* __restrict__ Bt,
    void* __restrict__ Cv, void* __restrict__ Cv2, int M, int N, int K,
    const int* __restrict__ meta, int e,
    const int* __restrict__ tokidx, const float* __restrict__ tokgate,
    const float* __restrict__ aux2) {
    const size_t CC_ = (size_t)Cdim * Cdim;
    int rows = M;
    int offA = 0;
    int outoff = 0;
    const __hip_bfloat16* Bp = Bt;
    const int* sidx = nullptr;
    const float* sgate = nullptr;
    if (meta) {
        if (EP == EP_TANHB) {
            rows = meta[6] + meta[7];
        } else if (EP == EP_KV) {
            int zx = blockIdx.z;                  // expert 6+zx
            rows = meta[6 + zx] * 4;
            offA = (meta[8 + 6 + zx] - meta[14]) * 4;
            outoff = offA;
            Bp = Bt + (size_t)(zx * 4) * CC_;     // [Wk|Wv] pair
        } else if (EP == EP_Q) {
            int zx = blockIdx.z;
            rows = meta[6 + zx];
            offA = meta[8 + 6 + zx];
            outoff = meta[8 + 6 + zx] - meta[14];
            Bp = Bt + (size_t)(zx * 4 + 2) * CC_; // Wq
        } else if (EP == EP_MOE) {
            int zx = blockIdx.z;                  // expert 6+zx, both in one dispatch
            rows = meta[6 + zx];
            offA = meta[8 + 6 + zx] - meta[14];   // attnc is lp-indexed
            sidx = tokidx + meta[8 + 6 + zx];
            sgate = tokgate + meta[8 + 6 + zx];
            Bp = Bt + (size_t)(zx * 4 + 3) * CC_; // Wo
        } else if (EP == EP_MOEM) {
            rows = meta[e];
            sidx = tokidx + meta[8 + e];
            sgate = tokgate + meta[8 + e];
        } else {
            rows = meta[e];
            offA = meta[8 + e];
        }
    }
    int m0 = blockIdx.y * 128;
    if (m0 >= rows) return;

    __shared__ __align__(16) __hip_bfloat16 Asm[8192];
    __shared__ __align__(16) __hip_bfloat16 Bsm[8192];
    int tid = threadIdx.x;
    int n0 = blockIdx.x * 128;
    int l = tid & 63, wv = tid >> 6;
    int wm = (wv >> 1) * 64, wn = (wv & 1) * 64;
    int lr = l & 15, lq = l >> 4;

    f32x4 acc[4][4];
#pragma unroll
    for (int i = 0; i < 4; i++)
#pragma unroll
        for (int j = 0; j < 4; j++) acc[i][j] = (f32x4){0.f, 0.f, 0.f, 0.f};

    int srow = tid >> 3;
    int sq = (tid & 7) ^ (srow & 7);
    size_t arow = (size_t)(m0 + offA + srow) * K + (sq << 3);
    size_t brow = (size_t)(n0 + srow) * K + (sq << 3);

    int kbeg, kend;
    if (EP == EP_KV || EP == EP_Q || EP == EP_MOE) {  // z = expert, no k-split
        kbeg = 0; kend = K;
    } else {
        int ks = K / gridDim.z;
        kbeg = blockIdx.z * ks; kend = kbeg + ks;
    }

    for (int kt = kbeg; kt < kend; kt += 64) {
#pragma unroll
        for (int c = 0; c < 4; c++) {
            size_t go = (size_t)(c * 32) * K + kt;
            gl_lds16(A + arow + go, Asm + c * 2048 + tid * 8);
            gl_lds16(Bp + brow + go, Bsm + c * 2048 + tid * 8);
        }
        __syncthreads();
#pragma unroll
        for (int kc = 0; kc < 64; kc += 32) {
            bfrag af[4], bf[4];
#pragma unroll
            for (int mi = 0; mi < 4; mi++) {
                int rr = wm + mi * 16 + lr;
                af[mi] = *(const bfrag*)&Asm[rr * 64 + ((((kc >> 3) + lq) ^ (rr & 7)) << 3)];
            }
#pragma unroll
            for (int ni = 0; ni < 4; ni++) {
                int rr = wn + ni * 16 + lr;
                bf[ni] = *(const bfrag*)&Bsm[rr * 64 + ((((kc >> 3) + lq) ^ (rr & 7)) << 3)];
            }
#pragma unroll
            for (int mi = 0; mi < 4; mi++)
#pragma unroll
                for (int ni = 0; ni < 4; ni++)
                    acc[mi][ni] = __builtin_amdgcn_mfma_f32_16x16x32_bf16(
                        af[mi], bf[ni], acc[mi][ni], 0, 0, 0);
        }
        __syncthreads();
    }

    float* Cf = (float*)Cv;
    __hip_bfloat16* Cb = (__hip_bfloat16*)Cv;
#pragma unroll
    for (int mi = 0; mi < 4; mi++) {
#pragma unroll
        for (int r = 0; r < 4; r++) {
            int row = m0 + wm + mi * 16 + lq * 4 + r;
            if (row >= rows) continue;
            int orow = row + outoff;
            int t = 0; float g = 0.f;
            if (EP == EP_MOE || EP == EP_MOEM) { t = sidx[row]; g = sgate[row]; }
#pragma unroll
            for (int ni = 0; ni < 4; ni++) {
                int col = n0 + wn + ni * 16 + lr;
                float v = acc[mi][ni][r];
                if (EP == EP_TANHB) {
                    Cb[(size_t)row * N + col] = __float2bfloat16(tanhf(v));
                } else if (EP == EP_Q) {
                    Cb[(size_t)orow * N + col] = __float2bfloat16(v);
                } else if (EP == EP_MOE) {
                    // both TR experts in one dispatch: winners {6,7} may target
                    // the same token row -> must be atomic
                    atomicAdd(Cf + (size_t)t * 1024 + col, g * v);
                } else if (EP == EP_MOEM) {
                    atomicAdd(Cf + (size_t)t * 1024 + col,
                              g * aux2[(size_t)row * 1024 + col] * v);
                } else if (EP == EP_FFN1) {
                    if ((col >> 10) == 0) {
                        Cf[(size_t)row * 1024 + col] = sigm(v);
                    } else {
                        float q = fmaxf(v, 0.f);
                        ((__hip_bfloat16*)Cv2)[(size_t)row * 4096 + col - 1024] =
                            __float2bfloat16(q * q);
                    }
                } else if (EP == EP_KV) {
                    if ((col >> 10) == 0)
                        Cb[(size_t)orow * 1024 + col] = __float2bfloat16(v);
                    else
                        ((__hip_bfloat16*)Cv2)[(size_t)orow * 1024 + col - 1024] =
                            __float2bfloat16(v);
                }
            }
        }
    }
}

// ---------------- chunked RWKV scan (3 passes) ----------------
__global__ __launch_bounds__(256) void scan_pass1(
    const float* __restrict__ k, const float* __restrict__ v,
    const float* __restrict__ w, float* __restrict__ Mbuf,
    float* __restrict__ Pbuf) {
    int c = blockIdx.x, bh = blockIdx.y;
    int b = bh >> 4, h = bh & 15;
    int tid = threadIdx.x, j = tid & 63, ig = tid >> 6;
    __shared__ float sbuf[2][3][64];
    float S[16], P[16];
#pragma unroll
    for (int ii = 0; ii < 16; ii++) { S[ii] = 0.f; P[ii] = 1.f; }

    size_t base = ((size_t)b * Tn + (size_t)c * CHL) * Cdim + (size_t)h * HSn + j;
    const float* srcs[3] = {k, v, w};
    const float* myp = (ig > 0) ? srcs[ig - 1] + base : k + base;

    const int CH = 8;
    float buf[CH];
#pragma unroll
    for (int u = 0; u < CH; u++) buf[u] = (ig > 0) ? myp[(size_t)u * Cdim] : 0.f;

    for (int tc = 0; tc < CHL; tc += CH) {
        float nbuf[CH];
#pragma unroll
        for (int u = 0; u < CH; u++) {
            int t2 = tc + CH + u;
            nbuf[u] = (ig > 0 && t2 < CHL) ? myp[(size_t)t2 * Cdim] : 0.f;
        }
#pragma unroll
        for (int u = 0; u < CH; u++) {
            int p = (tc + u) & 1;
            if (ig > 0) sbuf[p][ig - 1][j] = buf[u];
            __syncthreads();
            float vj = sbuf[p][1][j];
            const float* skp = sbuf[p][0];
            const float* swp = sbuf[p][2];
#pragma unroll
            for (int ii = 0; ii < 16; ii++) {
                int i = (ig << 4) + ii;
                float wi = swp[i];
                S[ii] = S[ii] * wi + skp[i] * vj;
                P[ii] *= wi;
            }
        }
#pragma unroll
        for (int u = 0; u < CH; u++) buf[u] = nbuf[u];
    }
    size_t mo = ((size_t)c * 32 + bh) * 4096;
#pragma unroll
    for (int ii = 0; ii < 16; ii++)
        Mbuf[mo + (size_t)((ig << 4) + ii) * 64 + j] = S[ii];
    if (j == 0) {
#pragma unroll
        for (int ii = 0; ii < 16; ii++)
            Pbuf[((size_t)c * 32 + bh) * 64 + (ig << 4) + ii] = P[ii];
    }
}

__global__ __launch_bounds__(256) void scan_pass2(
    const float* __restrict__ Mbuf, const float* __restrict__ Pbuf,
    float* __restrict__ Sinb) {
    int bh = blockIdx.y;
    int idx = blockIdx.x * 256 + threadIdx.x;
    int i = idx >> 6;
    float S = 0.f;
    for (int c = 0; c < NCH; c++) {
        size_t o = ((size_t)c * 32 + bh);
        Sinb[o * 4096 + idx] = S;
        S = Pbuf[o * 64 + i] * S + Mbuf[o * 4096 + idx];
    }
}

__global__ __launch_bounds__(256) void scan_pass3(
    const float* __restrict__ r, const float* __restrict__ k,
    const float* __restrict__ v, const float* __restrict__ w,
    const float* __restrict__ Sinb,
    __hip_bfloat16* __restrict__ sh, __hip_bfloat16* __restrict__ sl) {
    int c = blockIdx.x, bh = blockIdx.y;
    int b = bh >> 4, h = bh & 15;
    int tid = threadIdx.x, j = tid & 63, ig = tid >> 6;
    __shared__ float sbuf[2][4][64];
    __shared__ float red[2][4][64];
    float S[16];
    size_t so = ((size_t)c * 32 + bh) * 4096;
#pragma unroll
    for (int ii = 0; ii < 16; ii++)
        S[ii] = Sinb[so + (size_t)((ig << 4) + ii) * 64 + j];

    size_t base = ((size_t)b * Tn + (size_t)c * CHL) * Cdim + (size_t)h * HSn + j;
    const float* srcs[4] = {r, k, v, w};
    const float* myp = srcs[ig] + base;

    const int CH = 8;
    float buf[CH];
#pragma unroll
    for (int u = 0; u < CH; u++) buf[u] = myp[(size_t)u * Cdim];
    float part_prev = 0.f;

    for (int tc = 0; tc < CHL; tc += CH) {
        float nbuf[CH];
#pragma unroll
        for (int u = 0; u < CH; u++) {
            int t2 = tc + CH + u;
            nbuf[u] = (t2 < CHL) ? myp[(size_t)t2 * Cdim] : 0.f;
        }
#pragma unroll
        for (int u = 0; u < CH; u++) {
            int t = tc + u;
            int p = t & 1;
            sbuf[p][ig][j] = buf[u];
            red[p][ig][j] = part_prev;
            __syncthreads();
            if (ig == 0 && t > 0) {
                float val = red[p][0][j] + red[p][1][j] + red[p][2][j] + red[p][3][j];
                __hip_bfloat16 hi = __float2bfloat16(val);
                size_t pos = base + (size_t)(t - 1) * Cdim;
                sh[pos] = hi;
                sl[pos] = __float2bfloat16(val - __bfloat162float(hi));
            }
            float vj = sbuf[p][2][j];
            const float* srp = sbuf[p][0];
            const float* skp = sbuf[p][1];
            const float* swp = sbuf[p][3];
            float part = 0.f;
#pragma unroll
            for (int ii = 0; ii < 16; ii++) {
                int i = (ig << 4) + ii;
                S[ii] = S[ii] * swp[i] + skp[i] * vj;
                part += srp[i] * S[ii];
            }
            part_prev = part;
        }
#pragma unroll
        for (int u = 0; u < CH; u++) buf[u] = nbuf[u];
    }
    red[0][ig][j] = part_prev;
    __syncthreads();
    if (ig == 0) {
        float val = red[0][0][j] + red[0][1][j] + red[0][2][j] + red[0][3][j];
        __hip_bfloat16 hi = __float2bfloat16(val);
        size_t pos = base + (size_t)(CHL - 1) * Cdim;
        sh[pos] = hi;
        sl[pos] = __float2bfloat16(val - __bfloat162float(hi));
    }
}

// ---- deterministic position assignment + offsets (wave shuffle scan) ---------
// One block per expert; 2 barriers per 256-token chunk (was 16).
__global__ __launch_bounds__(256) void assign_kernel(
    const int2* __restrict__ winfo, const float2* __restrict__ gvals,
    int* __restrict__ meta, int* __restrict__ tokidx,
    float* __restrict__ tokgate, int2* __restrict__ posbuf) {
    int e = blockIdx.x;
    int tid = threadIdx.x, l = tid & 63, wid = tid >> 6;
    __shared__ int wsum[4];
    int base = 0;
    for (int e2 = 0; e2 < e; ++e2) base += meta[e2];
    if (tid == 0) meta[8 + e] = base;
    for (int c = 0; c < BTn; c += 256) {
        int t = c + tid;
        int2 w = winfo[t];
        int m0 = (w.x == e) ? 1 : 0;
        int m1 = (w.y == e) ? 1 : 0;
        int cnt = m0 + m1;          // w.x != w.y, so cnt is 0 or 1
        int xs = cnt;
#pragma unroll
        for (int off = 1; off < 64; off <<= 1) {
            int vv = __shfl_up(xs, off);
            if (l >= off) xs += vv;
        }
        if (l == 63) wsum[wid] = xs;
        __syncthreads();
        int pre = 0;
#pragma unroll
        for (int wj = 0; wj < 4; wj++) if (wj < wid) pre += wsum[wj];
        int tot = wsum[0] + wsum[1] + wsum[2] + wsum[3];
        int p = base + pre + xs - cnt;   // exclusive position
        if (m0) { tokidx[p] = t; tokgate[p] = gvals[t].x; posbuf[t].x = p; }
        if (m1) { tokidx[p] = t; tokgate[p] = gvals[t].y; posbuf[t].y = p; }
        base += tot;
        __syncthreads();                 // protect wsum before next chunk
    }
}

// ---------------- gather compact activations (pure copy, no atomics) -----------
__global__ __launch_bounds__(256) void gather_kernel(
    const __hip_bfloat16* __restrict__ h_bf, const __hip_bfloat16* __restrict__ st,
    const int2* __restrict__ winfo, const int2* __restrict__ posbuf,
    const int* __restrict__ meta,
    __hip_bfloat16* __restrict__ hc, __hip_bfloat16* __restrict__ hsc) {
    int t = blockIdx.x;
    int tid = threadIdx.x;
    int2 w = winfo[t];
    int2 p = posbuf[t];
    int off6 = meta[14];
    ushort4 hv = ((const ushort4*)(h_bf + (size_t)t * 1024))[tid];
    ((ushort4*)(hc + (size_t)p.x * 1024))[tid] = hv;
    ((ushort4*)(hc + (size_t)p.y * 1024))[tid] = hv;
    if (w.x >= 6) {
        int lp = p.x - off6;
        ((ushort4*)(hsc + (size_t)lp * 2048))[tid] = hv;
        ((ushort4*)(hsc + (size_t)lp * 2048 + 1024))[tid] =
            ((const ushort4*)(st + (size_t)t * 1024))[tid];
    }
    if (w.y >= 6) {
        int lp = p.y - off6;
        ((ushort4*)(hsc + (size_t)lp * 2048))[tid] = hv;
        ((ushort4*)(hsc + (size_t)lp * 2048 + 1024))[tid] =
            ((const ushort4*)(st + (size_t)t * 1024))[tid];
    }
}

// ------- transformer-expert prefix attention (both experts, lp-indexed) --------
__global__ __launch_bounds__(256) void tr_attn_kernel(
    const __hip_bfloat16* __restrict__ qc, const __hip_bfloat16* __restrict__ kpc,
    const __hip_bfloat16* __restrict__ vpc, __hip_bfloat16* __restrict__ attnc,
    const int* __restrict__ meta) {
    int cnt = meta[6] + meta[7];
    int idx = blockIdx.x * 4 + (threadIdx.x >> 6);   // lp * 16 + head
    int lane = threadIdx.x & 63;
    int n = idx >> 4, h = idx & 15;
    if (n >= cnt) return;
    float qd = __bfloat162float(qc[(size_t)n * Cdim + (size_t)h * HSn + lane]);
    float s[4];
#pragma unroll
    for (int p = 0; p < 4; p++) {
        float t = qd * __bfloat162float(kpc[((size_t)n * Pn + p) * Cdim + (size_t)h * HSn + lane]);
        for (int off = 32; off > 0; off >>= 1) t += __shfl_down(t, off);
        s[p] = __shfl(t, 0);
    }
    const float scale = 0.125f;
    float mx = fmaxf(fmaxf(s[0], s[1]), fmaxf(s[2], s[3])) * scale;
    float es = 0.f, a[4];
#pragma unroll
    for (int p = 0; p < 4; p++) { a[p] = expf(s[p] * scale - mx); es += a[p]; }
    float o = 0.f;
#pragma unroll
    for (int p = 0; p < 4; p++)
        o += (a[p] / es) * __bfloat162float(vpc[((size_t)n * Pn + p) * Cdim + (size_t)h * HSn + lane]);
    attnc[(size_t)n * Cdim + (size_t)h * HSn + lane] = __float2bfloat16(o);
}

// ---------------- orchestration ----------------
extern "C" void kernel_launch(void* const* d_in, const int* in_sizes, int n_in,
                              void* d_out, int out_size, void* d_ws, size_t ws_size,
                              hipStream_t stream) {
    const float* x      = (const float*)d_in[0];
    const float* cap    = (const float*)d_in[2];
    const float* ln1_w  = (const float*)d_in[3];
    const float* ln1_b  = (const float*)d_in[4];
    const float* ln2_w  = (const float*)d_in[5];
    const float* ln2_b  = (const float*)d_in[6];
    const float* Wr     = (const float*)d_in[7];
    const float* Wk     = (const float*)d_in[8];
    const float* Wv     = (const float*)d_in[9];
    const float* Ww     = (const float*)d_in[10];
    const float* w_bias = (const float*)d_in[11];
    const float* Wo     = (const float*)d_in[12];
    const float* conf_w = (const float*)d_in[13];
    const float* conf_b = (const float*)d_in[14];
    const float* Wa     = (const float*)d_in[17];
    const float* ba     = (const float*)d_in[18];
    const float* Wb     = (const float*)d_in[19];
    const float* ffn_Wr = (const float*)d_in[20];
    const float* ffn_Wk = (const float*)d_in[21];
    const float* ffn_Wv = (const float*)d_in[22];
    const float* tr_Wq  = (const float*)d_in[23];
    const float* tr_Wk  = (const float*)d_in[24];
    const float* tr_Wv  = (const float*)d_in[25];
    const float* tr_Wo  = (const float*)d_in[26];

    float* xout  = (float*)d_out;
    float* vflat = (float*)d_out + (size_t)BTn * Cdim;

    char* ws = (char*)d_ws;
    const size_t MB = 1ull << 20;
    // attention phase
    __hip_bfloat16* xln_hi  = (__hip_bfloat16*)(ws + 0 * MB);
    __hip_bfloat16* xln_lo  = (__hip_bfloat16*)(ws + 8 * MB);
    __hip_bfloat16* Wall_hi = (__hip_bfloat16*)(ws + 16 * MB);
    __hip_bfloat16* Wall_lo = (__hip_bfloat16*)(ws + 24 * MB);
    float*          rbuf    = (float*)(ws + 32 * MB);
    float*          kbuf    = (float*)(ws + 48 * MB);
    float*          wbuf    = (float*)(ws + 64 * MB);
    float*          Pbuf    = (float*)(ws + 80 * MB);
    __hip_bfloat16* Wo_hi   = (__hip_bfloat16*)(ws + 81 * MB);
    __hip_bfloat16* Wo_lo   = (__hip_bfloat16*)(ws + 83 * MB);
    float*          Mbuf    = (float*)(ws + 0 * MB);    // over xln (dead)
    float*          Sinb    = (float*)(ws + 8 * MB);
    __hip_bfloat16* st_hi   = (__hip_bfloat16*)(ws + 16 * MB);  // over Wall (dead)
    __hip_bfloat16* st_lo   = (__hip_bfloat16*)(ws + 24 * MB);
    __hip_bfloat16* h_bf    = (__hip_bfloat16*)(ws + 48 * MB);  // over kbuf (dead)
    // compact expert structures
    __hip_bfloat16* hc      = (__hip_bfloat16*)(ws + 56 * MB);  // 8320 rows, 56-74
    __hip_bfloat16* hsc     = (__hip_bfloat16*)(ws + 74 * MB);  // 74-108
    __hip_bfloat16* Wt_b    = (__hip_bfloat16*)(ws + 108 * MB); // 16MB, 108-124
    __hip_bfloat16* prefixc = (__hip_bfloat16*)(ws + 124 * MB); // 68MB, 124-192
    // FFN phase (hsc/Wt_b dead after prefix GEMM)
    __hip_bfloat16* eWall   = (__hip_bfloat16*)(ws + 0 * MB);   // 10MB
    __hip_bfloat16* eWv_t   = (__hip_bfloat16*)(ws + 10 * MB);  // 8MB
    float*          rg      = (float*)(ws + 18 * MB);           // 17MB, 18-35
    __hip_bfloat16* kk      = (__hip_bfloat16*)(ws + 74 * MB);  // 35MB, 74-109
    // TR phase (FFN temporaries dead); all lp-indexed (both experts contiguous)
    __hip_bfloat16* vpc     = (__hip_bfloat16*)(ws + 0 * MB);   // 34MB, 0-34
    __hip_bfloat16* tkv     = (__hip_bfloat16*)(ws + 34 * MB);  // 16MB (8 CxC), 34-50
    __hip_bfloat16* kpc     = (__hip_bfloat16*)(ws + 74 * MB);  // 34MB, 74-108
    __hip_bfloat16* qc      = (__hip_bfloat16*)(ws + 108 * MB); // 16MB, 108-124
    __hip_bfloat16* attnc   = (__hip_bfloat16*)(ws + 192 * MB); // 8MB, 192-200
    // routing metadata
    int*    meta    = (int*)(ws + 200 * MB);                    // [cnt8|off8|spare8]
    int*    tokidx  = (int*)(ws + 200 * MB + (64 << 10));
    float*  tokgate = (float*)(ws + 200 * MB + (128 << 10));
    int2*   winfo   = (int2*)(ws + 200 * MB + (192 << 10));
    float2* gvals   = (float2*)(ws + 200 * MB + (256 << 10));
    int2*   posbuf  = (int2*)(ws + 200 * MB + (320 << 10));
    (void)ws_size; (void)in_sizes; (void)n_in; (void)out_size;

    dim3 blk(256);
    auto grid = [](int M, int N) { return dim3(N / 128, M / 128); };
    const size_t CC = (size_t)Cdim * Cdim;

    // 0. weight conversions (vectorized + batched) + meta zero
    hipMemsetAsync(meta, 0, 96, stream);
    convT_split5_kernel<<<dim3(16, 16, 5), blk, 0, stream>>>(
        Wr, Wk, Wv, Ww, Wo, Wall_hi, Wall_lo, Wo_hi, Wo_lo);
    convT64_kernel<<<dim3(64, 32), blk, 0, stream>>>(Wb, Wt_b, 2 * Cdim, Pn * Cdim);

    // 1. ln1 -> hi/lo
    ln_kernel<<<BTn, blk, 0, stream>>>(x, ln1_w, ln1_b, nullptr, xln_hi, xln_lo);
    // 2. fused r/k/v/w projections (bf16x3, BK=64)
    bgemm3_kernel<EP3_QKVW><<<grid(BTn, 4 * Cdim), blk, 0, stream>>>(
        xln_hi, xln_lo, Wall_hi, Wall_lo, rbuf, kbuf, vflat, wbuf, BTn, 4 * Cdim, Cdim, w_bias);
    // 3. chunked scan
    scan_pass1<<<dim3(NCH, 32), blk, 0, stream>>>(kbuf, vflat, wbuf, Mbuf, Pbuf);
    scan_pass2<<<dim3(16, 32), blk, 0, stream>>>(Mbuf, Pbuf, Sinb);
    scan_pass3<<<dim3(NCH, 32), blk, 0, stream>>>(rbuf, kbuf, vflat, wbuf, Sinb, st_hi, st_lo);
    // 4. x_after_att = x + state @ Wo
    bgemm3_kernel<EP3_ADD><<<grid(BTn, Cdim), blk, 0, stream>>>(
        st_hi, st_lo, Wo_hi, Wo_lo, xout, nullptr, nullptr, nullptr, BTn, Cdim, Cdim, x);
    // 5+6. fused ln2 + routing (vectorized, 2 barriers)
    ln2_routing_kernel<<<BTn, blk, 0, stream>>>(
        xout, ln2_w, ln2_b, h_bf, conf_w, conf_b, Wa, ba, cap, meta, winfo, gvals);
    // 6b. deterministic compact-row assignment (wave shuffle scan)
    assign_kernel<<<dim3(8), blk, 0, stream>>>(winfo, gvals, meta, tokidx, tokgate, posbuf);
    // 7. gather compact activations (hc for all, hsc for TR winners)
    gather_kernel<<<BTn, blk, 0, stream>>>(h_bf, st_hi, winfo, posbuf, meta, hc, hsc);
    // 8. sparse bridge prefix = tanh(hsc @ Wb) over TR rows only
    bgemm_kernel<EP_TANHB><<<grid(2 * BTn, Pn * Cdim), blk, 0, stream>>>(
        hsc, Wt_b, prefixc, nullptr, 2 * BTn, Pn * Cdim, 2 * Cdim, meta, 0, nullptr, nullptr, nullptr);
    // 9. FFN experts (sparse); per-expert conversion batched into one z=9 dispatch
    for (int e = 0; e < NRn; e++) {
        convT_ffn_kernel<<<dim3(16, 16, 9), blk, 0, stream>>>(
            ffn_Wr + (size_t)e * CC, ffn_Wk + (size_t)e * Cdim * FFn,
            ffn_Wv + (size_t)e * FFn * Cdim, eWall, eWv_t);
        bgemm_kernel<EP_FFN1><<<grid(BTn, 5 * Cdim), blk, 0, stream>>>(
            hc, eWall, rg, kk, BTn, 5 * Cdim, Cdim, meta, e, nullptr, nullptr, nullptr);
        bgemm_kernel<EP_MOEM><<<dim3(Cdim / 128, BTn / 128, 2), blk, 0, stream>>>(
            kk, eWv_t, xout, nullptr, BTn, Cdim, FFn, meta, e, tokidx, tokgate, rg);
    }
    // 10. transformer experts, batched across both experts
    convT_tr8_kernel<<<dim3(16, 16, 8), blk, 0, stream>>>(tr_Wk, tr_Wv, tr_Wq, tr_Wo, tkv);
    bgemm_kernel<EP_KV><<<dim3(16, 128, 2), blk, 0, stream>>>(
        prefixc, tkv, kpc, vpc, 4 * BTn, 2 * Cdim, Cdim, meta, 6, nullptr, nullptr, nullptr);
    bgemm_kernel<EP_Q><<<dim3(8, 32, 2), blk, 0, stream>>>(
        hc, tkv, qc, nullptr, BTn, Cdim, Cdim, meta, 6, nullptr, nullptr, nullptr);
    tr_attn_kernel<<<(BTn * Hn) / 4, blk, 0, stream>>>(qc, kpc, vpc, attnc, meta);
    bgemm_kernel<EP_MOE><<<dim3(8, 32, 2), blk, 0, stream>>>(
        attnc, tkv, xout, nullptr, BTn, Cdim, Cdim, meta, 6, tokidx, tokgate, nullptr);
}